// Round 17
// baseline (384.597 us; speedup 1.0000x reference)
//
#include <hip/hip_runtime.h>
#include <math.h>

typedef float f32x4 __attribute__((ext_vector_type(4)));
typedef unsigned short ushort8 __attribute__((ext_vector_type(8)));
typedef unsigned short ushort4v __attribute__((ext_vector_type(4)));
typedef __bf16 bf16x8 __attribute__((ext_vector_type(8)));
typedef unsigned int u32;

__device__ __forceinline__ unsigned short f2bf(float x) {
  union { float f; unsigned u; } v; v.f = x;
  unsigned r = v.u + 0x7FFFu + ((v.u >> 16) & 1u);   // RNE
  return (unsigned short)(r >> 16);
}
__device__ __forceinline__ float bf2f(unsigned short u) {
  union { unsigned u; float f; } c; c.u = ((unsigned)u) << 16; return c.f;
}

__device__ __forceinline__ f32x4 mfma16(ushort8 a, ushort8 b, f32x4 c) {
  return __builtin_amdgcn_mfma_f32_16x16x32_bf16(
      __builtin_bit_cast(bf16x8, a), __builtin_bit_cast(bf16x8, b), c, 0, 0, 0);
}

// async global->LDS, 16B per lane; LDS dest = wave-uniform base, HW adds lane*16
__device__ __forceinline__ void gload16(const void* g, void* l) {
  __builtin_amdgcn_global_load_lds((const __attribute__((address_space(1))) u32*)g,
                                   (__attribute__((address_space(3))) u32*)l, 16, 0, 0);
}

// bijective XCD swizzle (m204): contiguous chunk of linear ids per XCD
__device__ __forceinline__ int xcd_swz(int orig, int nwg) {
  int q = nwg >> 3, r = nwg & 7;
  int xcd = orig & 7, lid = orig >> 3;
  return (xcd < r ? xcd * (q + 1) : r * (q + 1) + (xcd - r) * q) + lid;
}

// ---------------------------------------------------------------------------
// bf16 GEMM: C[M,N] = A[M,K] @ Bt[N,K]^T + bias. 128x128, BK=64.
// Depth-2 counted-vmcnt pipeline + XCD swizzle. Split-K via gridDim.z
// (slice z -> C + z*M*N, bias only z==0). Per-block A select: blocks with
// bn < nsplit read A, others A2 (for merged multi-source GEMMs).
// flags: 1 = relu, 2 = bf16 out
// ---------------------------------------------------------------------------
__global__ __launch_bounds__(256) void gemm_bf16_kernel(
    const unsigned short* __restrict__ A, const unsigned short* __restrict__ A2,
    int nsplit, const unsigned short* __restrict__ Bt,
    const float* __restrict__ bias, void* __restrict__ C,
    int M, int N, int K, int flags)
{
  __shared__ __align__(16) char As0[128 * 128];
  __shared__ __align__(16) char Bs0[128 * 128];
  __shared__ __align__(16) char As1[128 * 128];
  __shared__ __align__(16) char Bs1[128 * 128];
  const int gx = gridDim.x;
  const int wg = xcd_swz(blockIdx.x + gx * blockIdx.y, gx * gridDim.y);
  const int bn = wg % gx, bm = wg / gx;
  const int z = blockIdx.z;
  const int t = threadIdx.x;
  const int lane = t & 63, w = t >> 6, wm = w >> 1, wn = w & 1;
  const int l4 = lane & 15, lg = lane >> 4;
  const size_t K2 = (size_t)K * 2;

  f32x4 acc[4][4];
#pragma unroll
  for (int i = 0; i < 4; ++i)
#pragma unroll
    for (int j = 0; j < 4; ++j) acc[i][j] = f32x4{0.f, 0.f, 0.f, 0.f};

  const int lr = lane >> 3;
  const int ls = (lane & 7) ^ lr;
  const unsigned short* Ause = (bn < nsplit) ? A : A2;
  const char* Ag = (const char*)Ause + (size_t)(bm * 128 + w * 32 + lr) * K2 + ls * 16;
  const char* Bg = (const char*)Bt + (size_t)(bn * 128 + w * 32 + lr) * K2 + ls * 16;
  const int wo = w * 4096;

  auto STAGE = [&](char* Al, char* Bl, int kt) {
    const size_t ko = (size_t)kt * 128;
#pragma unroll
    for (int i = 0; i < 4; ++i) {
      gload16(Ag + i * 8 * K2 + ko, Al + wo + i * 1024);
      gload16(Bg + i * 8 * K2 + ko, Bl + wo + i * 1024);
    }
  };
  auto COMPUTE = [&](const char* As, const char* Bs) {
#pragma unroll
    for (int ks = 0; ks < 2; ++ks) {
      const int kb = ks * 64 + lg * 16;
      ushort8 af[4], bfr[4];
#pragma unroll
      for (int mi = 0; mi < 4; ++mi) {
        int r = wm * 64 + mi * 16 + l4;
        af[mi] = *reinterpret_cast<const ushort8*>(As + r * 128 + (kb ^ ((r & 7) << 4)));
      }
#pragma unroll
      for (int ni = 0; ni < 4; ++ni) {
        int r = wn * 64 + ni * 16 + l4;
        bfr[ni] = *reinterpret_cast<const ushort8*>(Bs + r * 128 + (kb ^ ((r & 7) << 4)));
      }
#pragma unroll
      for (int mi = 0; mi < 4; ++mi)
#pragma unroll
        for (int ni = 0; ni < 4; ++ni)
          acc[mi][ni] = mfma16(af[mi], bfr[ni], acc[mi][ni]);
    }
  };

#define GWAIT(more) do { if (more) asm volatile("s_waitcnt vmcnt(8)" ::: "memory"); \
                         else      asm volatile("s_waitcnt vmcnt(0)" ::: "memory"); } while (0)

  const int nkt2 = (K >> 6) / gridDim.z;   // even
  const int kbeg = z * nkt2, kend = kbeg + nkt2;
  STAGE(As0, Bs0, kbeg);
  STAGE(As1, Bs1, kbeg + 1);   // 16 loads/wave in flight
  for (int kt = kbeg; kt < kend; kt += 2) {
    GWAIT(kt + 1 < kend);
    __builtin_amdgcn_s_barrier();
    __builtin_amdgcn_sched_barrier(0);
    COMPUTE(As0, Bs0);
    __builtin_amdgcn_s_barrier();
    __builtin_amdgcn_sched_barrier(0);
    if (kt + 2 < kend) STAGE(As0, Bs0, kt + 2);
    GWAIT(kt + 2 < kend);
    __builtin_amdgcn_s_barrier();
    __builtin_amdgcn_sched_barrier(0);
    COMPUTE(As1, Bs1);
    __builtin_amdgcn_s_barrier();
    __builtin_amdgcn_sched_barrier(0);
    if (kt + 3 < kend) STAGE(As1, Bs1, kt + 3);
  }
#undef GWAIT

  const int relu = flags & 1, obf = flags & 2;
#pragma unroll
  for (int mi = 0; mi < 4; ++mi)
#pragma unroll
    for (int ni = 0; ni < 4; ++ni) {
      int col = bn * 128 + wn * 64 + ni * 16 + l4;
      float bia = (z == 0) ? bias[col] : 0.f;
#pragma unroll
      for (int j = 0; j < 4; ++j) {
        int row = bm * 128 + wm * 64 + mi * 16 + lg * 4 + j;
        float vv = acc[mi][ni][j] + bia;
        if (relu) vv = fmaxf(vv, 0.f);
        size_t idx = (size_t)z * M * N + (size_t)row * N + col;
        if (obf) ((unsigned short*)C)[idx] = f2bf(vv);
        else     ((float*)C)[idx] = vv;
      }
    }
}

// ---------------------------------------------------------------------------
// Flash attention, bf16, log2-domain softmax (Q pre-scaled by 0.125*log2e).
// QBLK=128 (8 waves x 16 q-rows), KVBLK=128 (8 iterations), 2 barriers/iter:
//   vmcnt(0); barrier1 -> prefetch(it+1) || V-write(it) || QK(it)
//   -> softmax -> P-write -> lgkmcnt(0); barrier2 -> PV(it)
// K double-buffered (gload_lds); V single-buffer [64d][128k] (row 256B,
// swizzle ^((dh&7)<<4)^((dh>>4)<<5)); P per-wave [16q][128k] (row 256B,
// swizzle ^((q&7)<<4)^((q&8)<<2)). Trigger-gated max; l via MFMA-ones.
// Race-free: PV(it-1) < barrier1(it) < V-write(it); all LDS writes drained
// per-wave (lgkmcnt) before barrier2; K buffer readers finished before the
// previous barrier2.
// ---------------------------------------------------------------------------
constexpr int kS = 1024, kD = 1024, kDH = 64;

__global__ __launch_bounds__(512) void attn_kernel(
    const unsigned short* __restrict__ Qg, const unsigned short* __restrict__ Kg,
    const unsigned short* __restrict__ Vg, int qs, int ks_,
    const unsigned short* __restrict__ mpack, unsigned short* __restrict__ Og)
{
  __shared__ __align__(16) char Ks0[16384];   // [128 keys][64 d]
  __shared__ __align__(16) char Ks1[16384];
  __shared__ __align__(16) char VTs[16384];   // [64 d][128 keys]
  __shared__ __align__(16) char Ps[32768];    // per-wave [16 q][128 k]
  const int wg = xcd_swz(blockIdx.x + 8 * (blockIdx.y + 16 * blockIdx.z), 512);
  const int qt = wg & 7, h = (wg >> 3) & 15, b = wg >> 7;
  const int t = threadIdx.x, lane = t & 63, w = t >> 6;   // w in 0..7
  const int l4 = lane & 15, lg = lane >> 4;
  const int lr = lane >> 3, sg = (lane & 7) ^ lr;

  // Q in registers: A-frag row = l4 (wave-local q-row), k = ks*32 + lg*8 + i
  ushort8 q0, q1;
  {
    const unsigned short* src = Qg + (size_t)(b * kS + qt * 128 + w * 16 + l4) * qs + h * kDH;
    q0 = *reinterpret_cast<const ushort8*>(src + lg * 8);
    q1 = *reinterpret_cast<const ushort8*>(src + 32 + lg * 8);
  }
  ushort8 onesv;
#pragma unroll
  for (int i = 0; i < 8; ++i) onesv[i] = 0x3F80;   // bf16 1.0

  // per-thread bitmask base: mpack[((b*8+qt)*16+kt)*512 + t] (kt = 64-key tile)
  const unsigned short* mtb = mpack + (size_t)(b * 8 + qt) * 8192 + t;

  // K tile (128 keys): wave w stages rows w*16+lr and w*16+8+lr
  auto stageK = [&](char* Kl, int it) {
    const char* base = (const char*)(Kg + (size_t)(b * kS + it * 128) * ks_ + h * kDH) + sg * 16;
    gload16(base + (size_t)(w * 16 + lr) * (ks_ * 2), Kl + w * 2048);
    gload16(base + (size_t)(w * 16 + 8 + lr) * (ks_ * 2), Kl + w * 2048 + 1024);
  };

  float m_r[4];
  f32x4 l_acc = f32x4{0.f, 0.f, 0.f, 0.f};
  f32x4 o[4];
#pragma unroll
  for (int j = 0; j < 4; ++j) m_r[j] = -1e30f;
#pragma unroll
  for (int di = 0; di < 4; ++di) o[di] = f32x4{0.f, 0.f, 0.f, 0.f};

  // V prefetch: thread t covers V[key = t>>2][(t&3)*16 .. +15] (2 x ushort8)
  ushort8 vA0, vA1, vB0, vB1;
  unsigned short mA0, mA1, mB0, mB1;
  stageK(Ks0, 0);
  {
    const unsigned short* vsrc = Vg + (size_t)(b * kS + (t >> 2)) * ks_ + h * kDH + (t & 3) * 16;
    vA0 = *reinterpret_cast<const ushort8*>(vsrc);
    vA1 = *reinterpret_cast<const ushort8*>(vsrc + 8);
    mA0 = mtb[0];
    mA1 = mtb[512];
  }

#define ATTN_IT(KC, KN, V0c, V1c, V0n, V1n, M0c, M1c, M0n, M1n, IT)                      \
  {                                                                                      \
    asm volatile("s_waitcnt vmcnt(0)" ::: "memory");                                     \
    __builtin_amdgcn_s_barrier();                          /* barrier1 */                \
    __builtin_amdgcn_sched_barrier(0);                                                   \
    if ((IT) + 1 < 8) { /* prefetch next iteration (flies under compute) */              \
      stageK(KN, (IT) + 1);                                                              \
      const unsigned short* vsrc = Vg +                                                  \
          (size_t)(b * kS + ((IT) + 1) * 128 + (t >> 2)) * ks_ + h * kDH + (t & 3) * 16; \
      V0n = *reinterpret_cast<const ushort8*>(vsrc);                                     \
      V1n = *reinterpret_cast<const ushort8*>(vsrc + 8);                                 \
      M0n = mtb[(2 * (IT) + 2) * 512];                                                   \
      M1n = mtb[(2 * (IT) + 3) * 512];                                                   \
    }                                                                                    \
    { /* V(it) transpose write into VTs (free: PV(it-1) < barrier1) */                   \
      int key2 = (t >> 2) * 2, c0 = (t & 3) * 16;                                        \
      _Pragma("unroll")                                                                  \
      for (int i = 0; i < 8; ++i) {                                                      \
        int dh = c0 + i;                                                                 \
        *(unsigned short*)(VTs + dh * 256 +                                              \
            (key2 ^ ((dh & 7) << 4) ^ ((dh >> 4) << 5))) = V0c[i];                       \
      }                                                                                  \
      _Pragma("unroll")                                                                  \
      for (int i = 0; i < 8; ++i) {                                                      \
        int dh = c0 + 8 + i;                                                             \
        *(unsigned short*)(VTs + dh * 256 +                                              \
            (key2 ^ ((dh & 7) << 4) ^ ((dh >> 4) << 5))) = V1c[i];                       \
      }                                                                                  \
    }                                                                                    \
    f32x4 sc[8];                                                                         \
    _Pragma("unroll")                                                                    \
    for (int ni = 0; ni < 8; ++ni) sc[ni] = f32x4{0.f, 0.f, 0.f, 0.f};                   \
    __builtin_amdgcn_s_setprio(1);                                                       \
    _Pragma("unroll")                                                                    \
    for (int ks = 0; ks < 2; ++ks) {                                                     \
      const int kb = ks * 64 + lg * 16;                                                  \
      ushort8 a = ks ? q1 : q0;                                                          \
      _Pragma("unroll")                                                                  \
      for (int ni = 0; ni < 8; ++ni) {                                                   \
        int kr = ni * 16 + l4;                                                           \
        ushort8 bb = *(const ushort8*)(KC + kr * 128 + (kb ^ ((kr & 7) << 4)));          \
        sc[ni] = mfma16(a, bb, sc[ni]);                                                  \
      }                                                                                  \
    }                                                                                    \
    __builtin_amdgcn_s_setprio(0);                                                       \
    const unsigned mb0_ = (unsigned)(M0c), mb1_ = (unsigned)(M1c);                       \
    float tmax[4];                                                                       \
    _Pragma("unroll")                                                                    \
    for (int j = 0; j < 4; ++j) {                                                        \
      _Pragma("unroll")                                                                  \
      for (int ni = 0; ni < 4; ++ni)                                                     \
        if (!((mb0_ >> (ni * 4 + j)) & 1u)) sc[ni][j] = -1e9f;                           \
      _Pragma("unroll")                                                                  \
      for (int ni = 4; ni < 8; ++ni)                                                     \
        if (!((mb1_ >> ((ni - 4) * 4 + j)) & 1u)) sc[ni][j] = -1e9f;                     \
      float t0 = fmaxf(fmaxf(sc[0][j], sc[1][j]), fmaxf(sc[2][j], sc[3][j]));            \
      float t1 = fmaxf(fmaxf(sc[4][j], sc[5][j]), fmaxf(sc[6][j], sc[7][j]));            \
      tmax[j] = fmaxf(t0, t1);                                                           \
    }                                                                                    \
    bool need = (tmax[0] > m_r[0] + 8.f) || (tmax[1] > m_r[1] + 8.f) ||                  \
                (tmax[2] > m_r[2] + 8.f) || (tmax[3] > m_r[3] + 8.f);                    \
    if (__any(need)) { /* rare after first iter: full reduce + rescale */                \
      _Pragma("unroll")                                                                  \
      for (int j = 0; j < 4; ++j) {                                                      \
        tmax[j] = fmaxf(tmax[j], __shfl_xor(tmax[j], 1, 64));                            \
        tmax[j] = fmaxf(tmax[j], __shfl_xor(tmax[j], 2, 64));                            \
        tmax[j] = fmaxf(tmax[j], __shfl_xor(tmax[j], 4, 64));                            \
        tmax[j] = fmaxf(tmax[j], __shfl_xor(tmax[j], 8, 64));                            \
        float mn = fmaxf(m_r[j], tmax[j]);                                               \
        float al = exp2f(m_r[j] - mn);                                                   \
        m_r[j] = mn;                                                                     \
        o[0][j] *= al; o[1][j] *= al; o[2][j] *= al; o[3][j] *= al;                      \
        l_acc[j] *= al;                                                                  \
      }                                                                                  \
    }                                                                                    \
    _Pragma("unroll")                                                                    \
    for (int ni = 0; ni < 8; ++ni)                                                       \
      _Pragma("unroll")                                                                  \
      for (int j = 0; j < 4; ++j)                                                        \
        sc[ni][j] = exp2f(sc[ni][j] - m_r[j]);                                           \
    { /* P -> per-wave LDS region (row 256B, conflict-free swizzle) */                   \
      char* Pw = Ps + w * 4096;                                                          \
      _Pragma("unroll")                                                                  \
      for (int ni = 0; ni < 8; ++ni)                                                     \
        _Pragma("unroll")                                                                \
        for (int j = 0; j < 4; ++j) {                                                    \
          int row = lg * 4 + j, col = ni * 16 + l4;                                      \
          *(unsigned short*)(Pw + row * 256 +                                            \
              ((col * 2) ^ ((row & 7) << 4) ^ ((row & 8) << 2))) =                       \
              __builtin_bit_cast(unsigned short, (__bf16)sc[ni][j]);                     \
        }                                                                                \
    }                                                                                    \
    asm volatile("s_waitcnt lgkmcnt(0)" ::: "memory");                                   \
    __builtin_amdgcn_s_barrier();                          /* barrier2 */                \
    __builtin_amdgcn_sched_barrier(0);                                                   \
    __builtin_amdgcn_s_setprio(1);                                                       \
    { /* PV + l-accumulation via ones-MFMA (keys 128 = 4 k-steps) */                     \
      const char* Pw = Ps + w * 4096;                                                    \
      _Pragma("unroll")                                                                  \
      for (int ks = 0; ks < 4; ++ks) {                                                   \
        const int kb = ks * 64 + lg * 16;                                                \
        ushort8 pa = *(const ushort8*)(Pw + l4 * 256 +                                   \
            (kb ^ ((l4 & 7) << 4) ^ ((l4 & 8) << 2)));                                   \
        l_acc = mfma16(pa, onesv, l_acc);                                                \
        _Pragma("unroll")                                                                \
        for (int di = 0; di < 4; ++di) {                                                 \
          int vr2 = di * 16 + l4;                                                        \
          ushort8 vb = *(const ushort8*)(VTs + vr2 * 256 +                               \
              (kb ^ ((vr2 & 7) << 4) ^ ((vr2 >> 4) << 5)));                              \
          o[di] = mfma16(pa, vb, o[di]);                                                 \
        }                                                                                \
      }                                                                                  \
    }                                                                                    \
    __builtin_amdgcn_s_setprio(0);                                                       \
  }

  for (int it = 0; it < 8; it += 2) {
    ATTN_IT(Ks0, Ks1, vA0, vA1, vB0, vB1, mA0, mA1, mB0, mB1, it);
    ATTN_IT(Ks1, Ks0, vB0, vB1, vA0, vA1, mB0, mB1, mA0, mA1, it + 1);
  }
#undef ATTN_IT

  // epilogue: l_acc[j] already holds the full row sum for q = lg*4+j
  float rinv[4];
#pragma unroll
  for (int j = 0; j < 4; ++j) rinv[j] = 1.0f / l_acc[j];
#pragma unroll
  for (int di = 0; di < 4; ++di) {
    int col = h * kDH + di * 16 + l4;
#pragma unroll
    for (int j = 0; j < 4; ++j) {
      int qrow = qt * 128 + w * 16 + lg * 4 + j;
      Og[(size_t)(b * kS + qrow) * kD + col] =
          __builtin_bit_cast(unsigned short, (__bf16)(o[di][j] * rinv[j]));
    }
  }
}

// ---------------------------------------------------------------------------
// out = LayerNorm(x + y0 + y1) * g + be (D=1024); all bf16 inputs; bf16 out
// and/or f32 out (either pointer may be null).
// ---------------------------------------------------------------------------
__global__ __launch_bounds__(256) void addln_kernel(
    const unsigned short* __restrict__ x, const unsigned short* __restrict__ y0,
    const unsigned short* __restrict__ y1,
    const float* __restrict__ g, const float* __restrict__ be,
    unsigned short* __restrict__ outb, float* __restrict__ outf)
{
  const int row = blockIdx.x, t = threadIdx.x;
  const size_t base = (size_t)row * 1024 + t * 4;
  ushort4v xv = *reinterpret_cast<const ushort4v*>(x + base);
  ushort4v yv0 = *reinterpret_cast<const ushort4v*>(y0 + base);
  ushort4v yv1 = *reinterpret_cast<const ushort4v*>(y1 + base);
  float v0 = bf2f(xv[0]) + bf2f(yv0[0]) + bf2f(yv1[0]);
  float v1 = bf2f(xv[1]) + bf2f(yv0[1]) + bf2f(yv1[1]);
  float v2 = bf2f(xv[2]) + bf2f(yv0[2]) + bf2f(yv1[2]);
  float v3 = bf2f(xv[3]) + bf2f(yv0[3]) + bf2f(yv1[3]);
  float s1 = v0 + v1 + v2 + v3;
  float s2 = v0 * v0 + v1 * v1 + v2 * v2 + v3 * v3;
#pragma unroll
  for (int off = 1; off < 64; off <<= 1) {
    s1 += __shfl_xor(s1, off, 64);
    s2 += __shfl_xor(s2, off, 64);
  }
  __shared__ float r1[4], r2[4];
  const int w = t >> 6, lane = t & 63;
  if (lane == 0) { r1[w] = s1; r2[w] = s2; }
  __syncthreads();
  s1 = r1[0] + r1[1] + r1[2] + r1[3];
  s2 = r2[0] + r2[1] + r2[2] + r2[3];
  const float mean = s1 * (1.0f / 1024.0f);
  const float var = s2 * (1.0f / 1024.0f) - mean * mean;
  const float rs = rsqrtf(var + 1e-5f);
  float4 gv = *reinterpret_cast<const float4*>(g + t * 4);
  float4 bv = *reinterpret_cast<const float4*>(be + t * 4);
  float4 ov;
  ov.x = (v0 - mean) * rs * gv.x + bv.x;
  ov.y = (v1 - mean) * rs * gv.y + bv.y;
  ov.z = (v2 - mean) * rs * gv.z + bv.z;
  ov.w = (v3 - mean) * rs * gv.w + bv.w;
  if (outb) {
    ushort4v bo;
    bo[0] = f2bf(ov.x); bo[1] = f2bf(ov.y); bo[2] = f2bf(ov.z); bo[3] = f2bf(ov.w);
    *reinterpret_cast<ushort4v*>(outb + base) = bo;
  }
  if (outf) *reinterpret_cast<float4*>(outf + base) = ov;
}

// ---------------------------------------------------------------------------
__global__ __launch_bounds__(256) void cvt2_bf16_kernel(
    const float* __restrict__ a, const float* __restrict__ b,
    unsigned short* __restrict__ da, unsigned short* __restrict__ db, int n8each)
{
  int i = blockIdx.x * 256 + threadIdx.x;
  const float* s = a; unsigned short* d = da;
  if (i >= n8each) { s = b; d = db; i -= n8each; }
  if (i >= n8each) return;
  float4 f0 = reinterpret_cast<const float4*>(s)[i * 2];
  float4 f1 = reinterpret_cast<const float4*>(s)[i * 2 + 1];
  ushort8 v;
  v[0] = f2bf(f0.x); v[1] = f2bf(f0.y); v[2] = f2bf(f0.z); v[3] = f2bf(f0.w);
  v[4] = f2bf(f1.x); v[5] = f2bf(f1.y); v[6] = f2bf(f1.z); v[7] = f2bf(f1.w);
  reinterpret_cast<ushort8*>(d)[i] = v;
}

// W[K][N] f32 -> Wt[n][k] bf16 (dst stride = K)
__global__ __launch_bounds__(256) void transpose_cvt_kernel(
    const float* __restrict__ src, unsigned short* __restrict__ dst, int K, int N)
{
  __shared__ float tile[32][33];
  const int bx = blockIdx.x, by = blockIdx.y;
  const int tx = threadIdx.x & 31, ty = threadIdx.x >> 5;
#pragma unroll
  for (int i = 0; i < 4; ++i)
    tile[ty + i * 8][tx] = src[(size_t)(by * 32 + ty + i * 8) * N + bx * 32 + tx];
  __syncthreads();
#pragma unroll
  for (int i = 0; i < 4; ++i)
    dst[(size_t)(bx * 32 + ty + i * 8) * K + by * 32 + tx] = f2bf(tile[tx][ty + i * 8]);
}

// batched 1024x1024 transposes with per-entry scale, grid (32,32,8)
struct TPtrs { const float* s[8]; unsigned short* d[8]; float scale[8]; };
__global__ __launch_bounds__(256) void tcvt_batch_kernel(TPtrs p)
{
  __shared__ float tile[32][33];
  const float* __restrict__ src = p.s[blockIdx.z];
  unsigned short* __restrict__ dst = p.d[blockIdx.z];
  const float sc = p.scale[blockIdx.z];
  const int bx = blockIdx.x, by = blockIdx.y;
  const int tx = threadIdx.x & 31, ty = threadIdx.x >> 5;
#pragma unroll
  for (int i = 0; i < 4; ++i)
    tile[ty + i * 8][tx] = src[(size_t)(by * 32 + ty + i * 8) * 1024 + bx * 32 + tx];
  __syncthreads();
#pragma unroll
  for (int i = 0; i < 4; ++i)
    dst[(size_t)(bx * 32 + ty + i * 8) * 1024 + by * 32 + tx] = f2bf(tile[tx][ty + i * 8] * sc);
}

__global__ void biasprep_kernel(const float* sq, const float* sk, const float* sv,
                                const float* cq, const float* ck, const float* cv,
                                float* bsa, float* bca, float s)
{
  int i = blockIdx.x * 256 + threadIdx.x;
  if (i < 1024)      { bsa[i] = sq[i] * s;        bca[i] = cq[i] * s; }
  else if (i < 2048) { bsa[i] = sk[i - 1024];     bca[i] = ck[i - 1024]; }
  else if (i < 3072) { bsa[i] = sv[i - 2048];     bca[i] = cv[i - 2048]; }
}

// mask int32 -> per-attn-thread 16-bit bitmask (512-thread blocks):
// mpack[((b*8+qt)*16+kt)*512 + t], bit (ni*4+j) = mask for
// q = qt*128 + ((t>>6)&7)*16 + ((t>>4)&3)*4 + j,  k = kt*64 + ni*16 + (t&15)
__global__ __launch_bounds__(256) void maskprep_kernel(
    const int* __restrict__ mask, unsigned short* __restrict__ mpack)
{
  int idx = blockIdx.x * 256 + threadIdx.x;   // 262144 slots
  int t = idx & 511;
  int kt = (idx >> 9) & 15;
  int qt = (idx >> 13) & 7;
  int b = idx >> 16;
  int qb = qt * 128 + ((t >> 6) & 7) * 16 + ((t >> 4) & 3) * 4;
  int kb = kt * 64 + (t & 15);
  unsigned m = 0;
#pragma unroll
  for (int ni = 0; ni < 4; ++ni)
#pragma unroll
    for (int j = 0; j < 4; ++j)
      if (mask[(size_t)(b * 1024 + qb + j) * 1024 + kb + ni * 16]) m |= 1u << (ni * 4 + j);
  mpack[idx] = (unsigned short)m;
}

// ---------------------------------------------------------------------------
extern "C" void kernel_launch(void* const* d_in, const int* in_sizes, int n_in,
                              void* d_out, int out_size, void* d_ws, size_t ws_size,
                              hipStream_t stream)
{
  const float* tgt  = (const float*)d_in[0];
  const float* memi = (const float*)d_in[1];
  const int*   mask = (const int*)d_in[2];
  const float* sa_wq = (const float*)d_in[3];  const float* sa_bq = (const float*)d_in[4];
  const float* sa_wk = (const float*)d_in[5];  const float* sa_bk = (const float*)d_in[6];
  const float* sa_wv = (const float*)d_in[7];  const float* sa_bv = (const float*)d_in[8];
  const float* sa_wo = (const float*)d_in[9];  const float* sa_bo = (const float*)d_in[10];
  const float* ca_wq = (const float*)d_in[11]; const float* ca_bq = (const float*)d_in[12];
  const float* ca_wk = (const float*)d_in[13]; const float* ca_bk = (const float*)d_in[14];
  const float* ca_wv = (const float*)d_in[15]; const float* ca_bv = (const float*)d_in[16];
  const float* ca_wo = (const float*)d_in[17]; const float* ca_bo = (const float*)d_in[18];
  const float* w1 = (const float*)d_in[19]; const float* b1 = (const float*)d_in[20];
  const float* w2 = (const float*)d_in[21]; const float* b2 = (const float*)d_in[22];
  const float* g1 = (const float*)d_in[23]; const float* be1 = (const float*)d_in[24];
  const float* g2 = (const float*)d_in[25]; const float* be2 = (const float*)d_in[26];
  const float* g3 = (const float*)d_in[27]; const float* be3 = (const float*)d_in[28];
  float* out = (float*)d_out;
  char* W = (char*)d_ws;
  const size_t MB = 1 << 20;
  typedef unsigned short us;
  const float QSCALE = 0.18033688011112042f;   // 0.125 * log2(e)

  // workspace layout (byte offsets; total ~106 MB).
  // NOTE: QKV spans 49-73MB, so T1b lives at 98MB (NOT inside 49-73).
  us* Wsaqkv = (us*)(W + 0);          // [3072][1024] bf16
  us* Wsao   = (us*)(W + 6 * MB);
  us* Wcaqkv = (us*)(W + 8 * MB);     // [3072][1024] = Wcaq | Wcakv contiguous
  us* Wcao   = (us*)(W + 14 * MB);
  us* W1t    = (us*)(W + 16 * MB);    // [4096][1024]
  us* W2t    = (us*)(W + 24 * MB);    // [1024][4096]
  float* b_saqkv = (float*)(W + 32 * MB);
  float* b_caqkv = (float*)(W + 32 * MB + 16384);
  us* tgt_bf = (us*)(W + 33 * MB);    // read by addln#1; then reused as T2b
  us* T2b    = tgt_bf;
  us* mem_bf = (us*)(W + 41 * MB);
  us* QKV    = (us*)(W + 49 * MB);    // [4096][3072] = 49-73MB (SA and CA reuse)
  us* AO     = (us*)(W + 73 * MB);    // [4096][1024] bf16, 73-81
  us* Hb     = (us*)(W + 49 * MB);    // FFN hidden [4096][4096] bf16 (49-81; QKV/AO dead)
  us* Opb    = (us*)(W + 81 * MB);    // TWO [4096][1024] bf16 partial slabs (81-97)
  us* mpack  = (us*)(W + 97 * MB);    // [4][8][16][512] ushort bitmasks, 512KB
  us* T1b    = (us*)(W + 98 * MB);    // [4096][1024] bf16, 98-106 (clear of QKV!)
  us* Opb1   = Opb + 4096 * 1024;

  const int M = 4096;
  dim3 blk(256);
  auto gemm = [&](const us* Aa, const us* Aa2, int nsplit, const us* Bta,
                  const float* bias, void* Cc, int Nn, int Kk, int flags, int zsplit) {
    gemm_bf16_kernel<<<dim3(Nn / 128, M / 128, zsplit), blk, 0, stream>>>(
        Aa, Aa2, nsplit, Bta, bias, Cc, M, Nn, Kk, flags);
  };

  // ---- prep ----
  TPtrs tp;
  tp.s[0] = sa_wq; tp.d[0] = Wsaqkv;               tp.scale[0] = QSCALE;
  tp.s[1] = sa_wk; tp.d[1] = Wsaqkv + 1024 * 1024; tp.scale[1] = 1.f;
  tp.s[2] = sa_wv; tp.d[2] = Wsaqkv + 2048 * 1024; tp.scale[2] = 1.f;
  tp.s[3] = sa_wo; tp.d[3] = Wsao;                 tp.scale[3] = 1.f;
  tp.s[4] = ca_wq; tp.d[4] = Wcaqkv;               tp.scale[4] = QSCALE;
  tp.s[5] = ca_wk; tp.d[5] = Wcaqkv + 1024 * 1024; tp.scale[5] = 1.f;
  tp.s[6] = ca_wv; tp.d[6] = Wcaqkv + 2048 * 1024; tp.scale[6] = 1.f;
  tp.s[7] = ca_wo; tp.d[7] = Wcao;                 tp.scale[7] = 1.f;
  tcvt_batch_kernel<<<dim3(32, 32, 8), blk, 0, stream>>>(tp);
  transpose_cvt_kernel<<<dim3(128, 32), blk, 0, stream>>>(w1, W1t, 1024, 4096);
  transpose_cvt_kernel<<<dim3(32, 128), blk, 0, stream>>>(w2, W2t, 4096, 1024);
  cvt2_bf16_kernel<<<dim3(4096), blk, 0, stream>>>(tgt, memi, tgt_bf, mem_bf, M * 1024 / 8);
  biasprep_kernel<<<dim3(12), blk, 0, stream>>>(sa_bq, sa_bk, sa_bv, ca_bq, ca_bk, ca_bv,
                                                b_saqkv, b_caqkv, QSCALE);
  maskprep_kernel<<<dim3(1024), blk, 0, stream>>>(mask, mpack);

  // ---- self-attention ----
  gemm(tgt_bf, tgt_bf, 1 << 30, Wsaqkv, b_saqkv, QKV, 3072, 1024, 2, 1);
  attn_kernel<<<dim3(8, 16, 4), dim3(512), 0, stream>>>(QKV, QKV + 1024, QKV + 2048, 3072, 3072, mpack, AO);
  gemm(AO, AO, 1 << 30, Wsao, sa_bo, Opb, 1024, 1024, 2, 2);   // split-K=2
  addln_kernel<<<dim3(M), blk, 0, stream>>>(tgt_bf, Opb, Opb1, g1, be1, T1b, nullptr);

  // ---- cross-attention (Q from T1b, K/V from mem_bf; one merged GEMM) ----
  gemm(T1b, mem_bf, 8, Wcaqkv, b_caqkv, QKV, 3072, 1024, 2, 1);
  attn_kernel<<<dim3(8, 16, 4), dim3(512), 0, stream>>>(QKV, QKV + 1024, QKV + 2048, 3072, 3072, mpack, AO);
  gemm(AO, AO, 1 << 30, Wcao, ca_bo, Opb, 1024, 1024, 2, 2);   // split-K=2
  addln_kernel<<<dim3(M), blk, 0, stream>>>(T1b, Opb, Opb1, g2, be2, T2b, nullptr);

  // ---- FFN ----
  gemm(T2b, T2b, 1 << 30, W1t, b1, Hb, 4096, 1024, 3, 1);
  gemm(Hb, Hb, 1 << 30, W2t, b2, Opb, 1024, 4096, 2, 2);       // split-K=2
  addln_kernel<<<dim3(M), blk, 0, stream>>>(T2b, Opb, Opb1, g3, be3, nullptr, out);

  (void)in_sizes; (void)n_in; (void)out_size; (void)ws_size;
}

// Round 18
// 379.405 us; speedup vs baseline: 1.0137x; 1.0137x over previous
//
#include <hip/hip_runtime.h>
#include <math.h>

typedef float f32x4 __attribute__((ext_vector_type(4)));
typedef unsigned short ushort8 __attribute__((ext_vector_type(8)));
typedef unsigned short ushort4v __attribute__((ext_vector_type(4)));
typedef __bf16 bf16x8 __attribute__((ext_vector_type(8)));
typedef unsigned int u32;

__device__ __forceinline__ unsigned short f2bf(float x) {
  union { float f; unsigned u; } v; v.f = x;
  unsigned r = v.u + 0x7FFFu + ((v.u >> 16) & 1u);   // RNE
  return (unsigned short)(r >> 16);
}
__device__ __forceinline__ float bf2f(unsigned short u) {
  union { unsigned u; float f; } c; c.u = ((unsigned)u) << 16; return c.f;
}

__device__ __forceinline__ f32x4 mfma16(ushort8 a, ushort8 b, f32x4 c) {
  return __builtin_amdgcn_mfma_f32_16x16x32_bf16(
      __builtin_bit_cast(bf16x8, a), __builtin_bit_cast(bf16x8, b), c, 0, 0, 0);
}

// async global->LDS, 16B per lane; LDS dest = wave-uniform base, HW adds lane*16
__device__ __forceinline__ void gload16(const void* g, void* l) {
  __builtin_amdgcn_global_load_lds((const __attribute__((address_space(1))) u32*)g,
                                   (__attribute__((address_space(3))) u32*)l, 16, 0, 0);
}

// bijective XCD swizzle (m204): contiguous chunk of linear ids per XCD
__device__ __forceinline__ int xcd_swz(int orig, int nwg) {
  int q = nwg >> 3, r = nwg & 7;
  int xcd = orig & 7, lid = orig >> 3;
  return (xcd < r ? xcd * (q + 1) : r * (q + 1) + (xcd - r) * q) + lid;
}

// ---------------------------------------------------------------------------
// bf16 GEMM: C[M,N] = A[M,K] @ Bt[N,K]^T + bias. 128x128, BK=64.
// Depth-2 counted-vmcnt pipeline + XCD swizzle. Split-K via gridDim.z
// (slice z -> C + z*M*N, bias only z==0). Per-block A select: blocks with
// bn < nsplit read A, others A2 (for merged multi-source GEMMs).
// flags: 1 = relu, 2 = bf16 out
// ---------------------------------------------------------------------------
__global__ __launch_bounds__(256) void gemm_bf16_kernel(
    const unsigned short* __restrict__ A, const unsigned short* __restrict__ A2,
    int nsplit, const unsigned short* __restrict__ Bt,
    const float* __restrict__ bias, void* __restrict__ C,
    int M, int N, int K, int flags)
{
  __shared__ __align__(16) char As0[128 * 128];
  __shared__ __align__(16) char Bs0[128 * 128];
  __shared__ __align__(16) char As1[128 * 128];
  __shared__ __align__(16) char Bs1[128 * 128];
  const int gx = gridDim.x;
  const int wg = xcd_swz(blockIdx.x + gx * blockIdx.y, gx * gridDim.y);
  const int bn = wg % gx, bm = wg / gx;
  const int z = blockIdx.z;
  const int t = threadIdx.x;
  const int lane = t & 63, w = t >> 6, wm = w >> 1, wn = w & 1;
  const int l4 = lane & 15, lg = lane >> 4;
  const size_t K2 = (size_t)K * 2;

  f32x4 acc[4][4];
#pragma unroll
  for (int i = 0; i < 4; ++i)
#pragma unroll
    for (int j = 0; j < 4; ++j) acc[i][j] = f32x4{0.f, 0.f, 0.f, 0.f};

  const int lr = lane >> 3;
  const int ls = (lane & 7) ^ lr;
  const unsigned short* Ause = (bn < nsplit) ? A : A2;
  const char* Ag = (const char*)Ause + (size_t)(bm * 128 + w * 32 + lr) * K2 + ls * 16;
  const char* Bg = (const char*)Bt + (size_t)(bn * 128 + w * 32 + lr) * K2 + ls * 16;
  const int wo = w * 4096;

  auto STAGE = [&](char* Al, char* Bl, int kt) {
    const size_t ko = (size_t)kt * 128;
#pragma unroll
    for (int i = 0; i < 4; ++i) {
      gload16(Ag + i * 8 * K2 + ko, Al + wo + i * 1024);
      gload16(Bg + i * 8 * K2 + ko, Bl + wo + i * 1024);
    }
  };
  auto COMPUTE = [&](const char* As, const char* Bs) {
#pragma unroll
    for (int ks = 0; ks < 2; ++ks) {
      const int kb = ks * 64 + lg * 16;
      ushort8 af[4], bfr[4];
#pragma unroll
      for (int mi = 0; mi < 4; ++mi) {
        int r = wm * 64 + mi * 16 + l4;
        af[mi] = *reinterpret_cast<const ushort8*>(As + r * 128 + (kb ^ ((r & 7) << 4)));
      }
#pragma unroll
      for (int ni = 0; ni < 4; ++ni) {
        int r = wn * 64 + ni * 16 + l4;
        bfr[ni] = *reinterpret_cast<const ushort8*>(Bs + r * 128 + (kb ^ ((r & 7) << 4)));
      }
#pragma unroll
      for (int mi = 0; mi < 4; ++mi)
#pragma unroll
        for (int ni = 0; ni < 4; ++ni)
          acc[mi][ni] = mfma16(af[mi], bfr[ni], acc[mi][ni]);
    }
  };

#define GWAIT(more) do { if (more) asm volatile("s_waitcnt vmcnt(8)" ::: "memory"); \
                         else      asm volatile("s_waitcnt vmcnt(0)" ::: "memory"); } while (0)

  const int nkt2 = (K >> 6) / gridDim.z;   // even
  const int kbeg = z * nkt2, kend = kbeg + nkt2;
  STAGE(As0, Bs0, kbeg);
  STAGE(As1, Bs1, kbeg + 1);   // 16 loads/wave in flight
  for (int kt = kbeg; kt < kend; kt += 2) {
    GWAIT(kt + 1 < kend);
    __builtin_amdgcn_s_barrier();
    __builtin_amdgcn_sched_barrier(0);
    COMPUTE(As0, Bs0);
    __builtin_amdgcn_s_barrier();
    __builtin_amdgcn_sched_barrier(0);
    if (kt + 2 < kend) STAGE(As0, Bs0, kt + 2);
    GWAIT(kt + 2 < kend);
    __builtin_amdgcn_s_barrier();
    __builtin_amdgcn_sched_barrier(0);
    COMPUTE(As1, Bs1);
    __builtin_amdgcn_s_barrier();
    __builtin_amdgcn_sched_barrier(0);
    if (kt + 3 < kend) STAGE(As1, Bs1, kt + 3);
  }
#undef GWAIT

  const int relu = flags & 1, obf = flags & 2;
#pragma unroll
  for (int mi = 0; mi < 4; ++mi)
#pragma unroll
    for (int ni = 0; ni < 4; ++ni) {
      int col = bn * 128 + wn * 64 + ni * 16 + l4;
      float bia = (z == 0) ? bias[col] : 0.f;
#pragma unroll
      for (int j = 0; j < 4; ++j) {
        int row = bm * 128 + wm * 64 + mi * 16 + lg * 4 + j;
        float vv = acc[mi][ni][j] + bia;
        if (relu) vv = fmaxf(vv, 0.f);
        size_t idx = (size_t)z * M * N + (size_t)row * N + col;
        if (obf) ((unsigned short*)C)[idx] = f2bf(vv);
        else     ((float*)C)[idx] = vv;
      }
    }
}

// ---------------------------------------------------------------------------
// Flash attention, bf16, log2-domain softmax (Q pre-scaled by 0.125*log2e).
// QBLK=128: block = (qt, h, b) XCD-swizzled, 512 threads = 8 waves x 16
// q-rows. Per-wave compute identical to the QBLK=64 version; staging split
// across 8 waves (stageK = 1 gload/wave; V = 1 ushort8/thread, 8 transpose
// writes). K/V tile amortized over 2x the q-rows. Round-14 tile schedule:
// V-write pre-barrier, single barrier/tile, PV in-tile after lgkmcnt(0);
// trigger-gated max; l via MFMA-ones.
// ---------------------------------------------------------------------------
constexpr int kS = 1024, kD = 1024, kDH = 64;

__global__ __launch_bounds__(512) void attn_kernel(
    const unsigned short* __restrict__ Qg, const unsigned short* __restrict__ Kg,
    const unsigned short* __restrict__ Vg, int qs, int ks_,
    const unsigned short* __restrict__ mpack, unsigned short* __restrict__ Og)
{
  __shared__ __align__(16) char Ks0[8192];
  __shared__ __align__(16) char Ks1[8192];
  __shared__ __align__(16) char VT0[8192];
  __shared__ __align__(16) char VT1[8192];
  __shared__ __align__(16) char Ps[16384];
  const int wg = xcd_swz(blockIdx.x + 8 * (blockIdx.y + 16 * blockIdx.z), 512);
  const int qt = wg & 7, h = (wg >> 3) & 15, b = wg >> 7;
  const int t = threadIdx.x, lane = t & 63, w = t >> 6;   // w in 0..7
  const int l4 = lane & 15, lg = lane >> 4;
  const int lr = lane >> 3, sg = (lane & 7) ^ lr;

  // Q in registers: A-frag row = l4 (wave-local q-row), k = ks*32 + lg*8 + i
  ushort8 q0, q1;
  {
    const unsigned short* src = Qg + (size_t)(b * kS + qt * 128 + w * 16 + l4) * qs + h * kDH;
    q0 = *reinterpret_cast<const ushort8*>(src + lg * 8);
    q1 = *reinterpret_cast<const ushort8*>(src + 32 + lg * 8);
  }
  ushort8 onesv;
#pragma unroll
  for (int i = 0; i < 8; ++i) onesv[i] = 0x3F80;   // bf16 1.0

  // per-thread bitmask base: mpack[((b*8+qt)*16+kt)*512 + t]
  const unsigned short* mtb = mpack + (size_t)(b * 8 + qt) * 8192 + t;

  // K tile: wave w stages rows w*8..w*8+7 (1KB); LDS row r slot s holds cols
  // (s^(r&7))*8..+7 (read: kb ^ ((r&7)<<4)) -- r&7 == lane>>3 within wave
  auto stageK = [&](char* Kl, int kt) {
    const char* base = (const char*)(Kg + (size_t)(b * kS + kt * 64) * ks_ + h * kDH) + sg * 16;
    gload16(base + (size_t)(w * 8 + lr) * (ks_ * 2), Kl + w * 1024);
  };

  float m_r[4];
  f32x4 l_acc = f32x4{0.f, 0.f, 0.f, 0.f};
  f32x4 o[4];
#pragma unroll
  for (int j = 0; j < 4; ++j) m_r[j] = -1e30f;
#pragma unroll
  for (int di = 0; di < 4; ++di) o[di] = f32x4{0.f, 0.f, 0.f, 0.f};

  // V prefetch: thread t covers V[key = t>>3][c0 = (t&7)*8 .. +7] (16B)
  ushort8 vA, vB;
  unsigned short mA, mB;
  stageK(Ks0, 0);
  {
    const unsigned short* vsrc = Vg + (size_t)(b * kS + (t >> 3)) * ks_ + h * kDH + (t & 7) * 8;
    vA = *reinterpret_cast<const ushort8*>(vsrc);
    mA = mtb[0];
  }

#define ATTN_TILE(KC, VC, KN, VCC, VNN, MCUR, MNXT, KTV)                                 \
  {                                                                                      \
    asm volatile("s_waitcnt vmcnt(0)" ::: "memory");                                     \
    { /* V(k) transpose write into VC BEFORE the barrier (conflict-free swizzle) */      \
      int key2 = (t >> 3) * 2, c0 = (t & 7) * 8;                                         \
      _Pragma("unroll")                                                                  \
      for (int i = 0; i < 8; ++i) {                                                      \
        int dh = c0 + i;                                                                 \
        *(unsigned short*)(VC + dh * 128 +                                               \
            (key2 ^ ((dh & 7) << 4) ^ ((dh >> 4) << 5))) = VCC[i];                       \
      }                                                                                  \
    }                                                                                    \
    asm volatile("s_waitcnt lgkmcnt(0)" ::: "memory");                                   \
    __builtin_amdgcn_s_barrier();                                                        \
    __builtin_amdgcn_sched_barrier(0);                                                   \
    if ((KTV) + 1 < 16) { /* prefetch next tile (flies under compute) */                 \
      stageK(KN, (KTV) + 1);                                                             \
      const unsigned short* vsrc = Vg +                                                  \
          (size_t)(b * kS + ((KTV) + 1) * 64 + (t >> 3)) * ks_ + h * kDH + (t & 7) * 8;  \
      VNN = *reinterpret_cast<const ushort8*>(vsrc);                                     \
      MNXT = mtb[((KTV) + 1) * 512];                                                     \
    }                                                                                    \
    f32x4 sc[4];                                                                         \
    _Pragma("unroll")                                                                    \
    for (int ni = 0; ni < 4; ++ni) sc[ni] = f32x4{0.f, 0.f, 0.f, 0.f};                   \
    __builtin_amdgcn_s_setprio(1);                                                       \
    _Pragma("unroll")                                                                    \
    for (int ks = 0; ks < 2; ++ks) {                                                     \
      const int kb = ks * 64 + lg * 16;                                                  \
      ushort8 a = ks ? q1 : q0;                                                          \
      _Pragma("unroll")                                                                  \
      for (int ni = 0; ni < 4; ++ni) {                                                   \
        int kr = ni * 16 + l4;                                                           \
        ushort8 bb = *(const ushort8*)(KC + kr * 128 + (kb ^ ((kr & 7) << 4)));          \
        sc[ni] = mfma16(a, bb, sc[ni]);                                                  \
      }                                                                                  \
    }                                                                                    \
    __builtin_amdgcn_s_setprio(0);                                                       \
    const unsigned mbits_ = (unsigned)(MCUR);                                            \
    float tmax[4];                                                                       \
    _Pragma("unroll")                                                                    \
    for (int j = 0; j < 4; ++j) {                                                        \
      _Pragma("unroll")                                                                  \
      for (int ni = 0; ni < 4; ++ni)                                                     \
        if (!((mbits_ >> (ni * 4 + j)) & 1u)) sc[ni][j] = -1e9f;                         \
      tmax[j] = fmaxf(fmaxf(sc[0][j], sc[1][j]), fmaxf(sc[2][j], sc[3][j]));             \
    }                                                                                    \
    bool need = (tmax[0] > m_r[0] + 8.f) || (tmax[1] > m_r[1] + 8.f) ||                  \
                (tmax[2] > m_r[2] + 8.f) || (tmax[3] > m_r[3] + 8.f);                    \
    if (__any(need)) { /* rare after first tile: full reduce + rescale */                \
      _Pragma("unroll")                                                                  \
      for (int j = 0; j < 4; ++j) {                                                      \
        tmax[j] = fmaxf(tmax[j], __shfl_xor(tmax[j], 1, 64));                            \
        tmax[j] = fmaxf(tmax[j], __shfl_xor(tmax[j], 2, 64));                            \
        tmax[j] = fmaxf(tmax[j], __shfl_xor(tmax[j], 4, 64));                            \
        tmax[j] = fmaxf(tmax[j], __shfl_xor(tmax[j], 8, 64));                            \
        float mn = fmaxf(m_r[j], tmax[j]);                                               \
        float al = exp2f(m_r[j] - mn);                                                   \
        m_r[j] = mn;                                                                     \
        o[0][j] *= al; o[1][j] *= al; o[2][j] *= al; o[3][j] *= al;                      \
        l_acc[j] *= al;                                                                  \
      }                                                                                  \
    }                                                                                    \
    _Pragma("unroll")                                                                    \
    for (int ni = 0; ni < 4; ++ni)                                                       \
      _Pragma("unroll")                                                                  \
      for (int j = 0; j < 4; ++j)                                                        \
        sc[ni][j] = exp2f(sc[ni][j] - m_r[j]);                                           \
    { /* P -> per-wave LDS region, conflict-free swizzle */                              \
      char* Pw = Ps + w * 2048;                                                          \
      _Pragma("unroll")                                                                  \
      for (int ni = 0; ni < 4; ++ni)                                                     \
        _Pragma("unroll")                                                                \
        for (int j = 0; j < 4; ++j) {                                                    \
          int row = lg * 4 + j, col = ni * 16 + l4;                                      \
          *(unsigned short*)(Pw + row * 128 +                                            \
              ((col * 2) ^ ((row & 7) << 4) ^ ((row & 8) << 2))) =                       \
              __builtin_bit_cast(unsigned short, (__bf16)sc[ni][j]);                     \
        }                                                                                \
    }                                                                                    \
    asm volatile("s_waitcnt lgkmcnt(0)" ::: "memory");                                   \
    __builtin_amdgcn_sched_barrier(0);                                                   \
    __builtin_amdgcn_s_setprio(1);                                                       \
    { /* PV + l-accumulation via ones-MFMA */                                            \
      const char* Pw = Ps + w * 2048;                                                    \
      _Pragma("unroll")                                                                  \
      for (int ks = 0; ks < 2; ++ks) {                                                   \
        const int kb = ks * 64 + lg * 16;                                                \
        ushort8 pa = *(const ushort8*)(Pw + l4 * 128 +                                   \
            (kb ^ ((l4 & 7) << 4) ^ ((l4 & 8) << 2)));                                   \
        l_acc = mfma16(pa, onesv, l_acc);                                                \
        _Pragma("unroll")                                                                \
        for (int di = 0; di < 4; ++di) {                                                 \
          int vr2 = di * 16 + l4;                                                        \
          ushort8 vb = *(const ushort8*)(VC + vr2 * 128 +                                \
              (kb ^ ((vr2 & 7) << 4) ^ ((vr2 >> 4) << 5)));                              \
          o[di] = mfma16(pa, vb, o[di]);                                                 \
        }                                                                                \
      }                                                                                  \
    }                                                                                    \
    __builtin_amdgcn_s_setprio(0);                                                       \
  }

  for (int kt = 0; kt < 16; kt += 2) {
    ATTN_TILE(Ks0, VT0, Ks1, vA, vB, mA, mB, kt);
    ATTN_TILE(Ks1, VT1, Ks0, vB, vA, mB, mA, kt + 1);
  }
#undef ATTN_TILE

  // epilogue: l_acc[j] already holds the full row sum for q = lg*4+j
  float rinv[4];
#pragma unroll
  for (int j = 0; j < 4; ++j) rinv[j] = 1.0f / l_acc[j];
#pragma unroll
  for (int di = 0; di < 4; ++di) {
    int col = h * kDH + di * 16 + l4;
#pragma unroll
    for (int j = 0; j < 4; ++j) {
      int qrow = qt * 128 + w * 16 + lg * 4 + j;
      Og[(size_t)(b * kS + qrow) * kD + col] =
          __builtin_bit_cast(unsigned short, (__bf16)(o[di][j] * rinv[j]));
    }
  }
}

// ---------------------------------------------------------------------------
// out = LayerNorm(x + y0 + y1) * g + be (D=1024); all bf16 inputs; bf16 out
// and/or f32 out (either pointer may be null).
// ---------------------------------------------------------------------------
__global__ __launch_bounds__(256) void addln_kernel(
    const unsigned short* __restrict__ x, const unsigned short* __restrict__ y0,
    const unsigned short* __restrict__ y1,
    const float* __restrict__ g, const float* __restrict__ be,
    unsigned short* __restrict__ outb, float* __restrict__ outf)
{
  const int row = blockIdx.x, t = threadIdx.x;
  const size_t base = (size_t)row * 1024 + t * 4;
  ushort4v xv = *reinterpret_cast<const ushort4v*>(x + base);
  ushort4v yv0 = *reinterpret_cast<const ushort4v*>(y0 + base);
  ushort4v yv1 = *reinterpret_cast<const ushort4v*>(y1 + base);
  float v0 = bf2f(xv[0]) + bf2f(yv0[0]) + bf2f(yv1[0]);
  float v1 = bf2f(xv[1]) + bf2f(yv0[1]) + bf2f(yv1[1]);
  float v2 = bf2f(xv[2]) + bf2f(yv0[2]) + bf2f(yv1[2]);
  float v3 = bf2f(xv[3]) + bf2f(yv0[3]) + bf2f(yv1[3]);
  float s1 = v0 + v1 + v2 + v3;
  float s2 = v0 * v0 + v1 * v1 + v2 * v2 + v3 * v3;
#pragma unroll
  for (int off = 1; off < 64; off <<= 1) {
    s1 += __shfl_xor(s1, off, 64);
    s2 += __shfl_xor(s2, off, 64);
  }
  __shared__ float r1[4], r2[4];
  const int w = t >> 6, lane = t & 63;
  if (lane == 0) { r1[w] = s1; r2[w] = s2; }
  __syncthreads();
  s1 = r1[0] + r1[1] + r1[2] + r1[3];
  s2 = r2[0] + r2[1] + r2[2] + r2[3];
  const float mean = s1 * (1.0f / 1024.0f);
  const float var = s2 * (1.0f / 1024.0f) - mean * mean;
  const float rs = rsqrtf(var + 1e-5f);
  float4 gv = *reinterpret_cast<const float4*>(g + t * 4);
  float4 bv = *reinterpret_cast<const float4*>(be + t * 4);
  float4 ov;
  ov.x = (v0 - mean) * rs * gv.x + bv.x;
  ov.y = (v1 - mean) * rs * gv.y + bv.y;
  ov.z = (v2 - mean) * rs * gv.z + bv.z;
  ov.w = (v3 - mean) * rs * gv.w + bv.w;
  if (outb) {
    ushort4v bo;
    bo[0] = f2bf(ov.x); bo[1] = f2bf(ov.y); bo[2] = f2bf(ov.z); bo[3] = f2bf(ov.w);
    *reinterpret_cast<ushort4v*>(outb + base) = bo;
  }
  if (outf) *reinterpret_cast<float4*>(outf + base) = ov;
}

// ---------------------------------------------------------------------------
__global__ __launch_bounds__(256) void cvt2_bf16_kernel(
    const float* __restrict__ a, const float* __restrict__ b,
    unsigned short* __restrict__ da, unsigned short* __restrict__ db, int n8each)
{
  int i = blockIdx.x * 256 + threadIdx.x;
  const float* s = a; unsigned short* d = da;
  if (i >= n8each) { s = b; d = db; i -= n8each; }
  if (i >= n8each) return;
  float4 f0 = reinterpret_cast<const float4*>(s)[i * 2];
  float4 f1 = reinterpret_cast<const float4*>(s)[i * 2 + 1];
  ushort8 v;
  v[0] = f2bf(f0.x); v[1] = f2bf(f0.y); v[2] = f2bf(f0.z); v[3] = f2bf(f0.w);
  v[4] = f2bf(f1.x); v[5] = f2bf(f1.y); v[6] = f2bf(f1.z); v[7] = f2bf(f1.w);
  reinterpret_cast<ushort8*>(d)[i] = v;
}

// W[K][N] f32 -> Wt[n][k] bf16 (dst stride = K)
__global__ __launch_bounds__(256) void transpose_cvt_kernel(
    const float* __restrict__ src, unsigned short* __restrict__ dst, int K, int N)
{
  __shared__ float tile[32][33];
  const int bx = blockIdx.x, by = blockIdx.y;
  const int tx = threadIdx.x & 31, ty = threadIdx.x >> 5;
#pragma unroll
  for (int i = 0; i < 4; ++i)
    tile[ty + i * 8][tx] = src[(size_t)(by * 32 + ty + i * 8) * N + bx * 32 + tx];
  __syncthreads();
#pragma unroll
  for (int i = 0; i < 4; ++i)
    dst[(size_t)(bx * 32 + ty + i * 8) * K + by * 32 + tx] = f2bf(tile[tx][ty + i * 8]);
}

// batched 1024x1024 transposes with per-entry scale, grid (32,32,8)
struct TPtrs { const float* s[8]; unsigned short* d[8]; float scale[8]; };
__global__ __launch_bounds__(256) void tcvt_batch_kernel(TPtrs p)
{
  __shared__ float tile[32][33];
  const float* __restrict__ src = p.s[blockIdx.z];
  unsigned short* __restrict__ dst = p.d[blockIdx.z];
  const float sc = p.scale[blockIdx.z];
  const int bx = blockIdx.x, by = blockIdx.y;
  const int tx = threadIdx.x & 31, ty = threadIdx.x >> 5;
#pragma unroll
  for (int i = 0; i < 4; ++i)
    tile[ty + i * 8][tx] = src[(size_t)(by * 32 + ty + i * 8) * 1024 + bx * 32 + tx];
  __syncthreads();
#pragma unroll
  for (int i = 0; i < 4; ++i)
    dst[(size_t)(bx * 32 + ty + i * 8) * 1024 + by * 32 + tx] = f2bf(tile[tx][ty + i * 8] * sc);
}

__global__ void biasprep_kernel(const float* sq, const float* sk, const float* sv,
                                const float* cq, const float* ck, const float* cv,
                                float* bsa, float* bca, float s)
{
  int i = blockIdx.x * 256 + threadIdx.x;
  if (i < 1024)      { bsa[i] = sq[i] * s;        bca[i] = cq[i] * s; }
  else if (i < 2048) { bsa[i] = sk[i - 1024];     bca[i] = ck[i - 1024]; }
  else if (i < 3072) { bsa[i] = sv[i - 2048];     bca[i] = cv[i - 2048]; }
}

// mask int32 -> per-attn-thread 16-bit bitmask (512-thread blocks):
// mpack[((b*8+qt)*16+kt)*512 + t], bit (ni*4+j) = mask for
// q = qt*128 + ((t>>6)&7)*16 + ((t>>4)&3)*4 + j,  k = kt*64 + ni*16 + (t&15)
__global__ __launch_bounds__(256) void maskprep_kernel(
    const int* __restrict__ mask, unsigned short* __restrict__ mpack)
{
  int idx = blockIdx.x * 256 + threadIdx.x;   // 262144 slots
  int t = idx & 511;
  int kt = (idx >> 9) & 15;
  int qt = (idx >> 13) & 7;
  int b = idx >> 16;
  int qb = qt * 128 + ((t >> 6) & 7) * 16 + ((t >> 4) & 3) * 4;
  int kb = kt * 64 + (t & 15);
  unsigned m = 0;
#pragma unroll
  for (int ni = 0; ni < 4; ++ni)
#pragma unroll
    for (int j = 0; j < 4; ++j)
      if (mask[(size_t)(b * 1024 + qb + j) * 1024 + kb + ni * 16]) m |= 1u << (ni * 4 + j);
  mpack[idx] = (unsigned short)m;
}

// ---------------------------------------------------------------------------
extern "C" void kernel_launch(void* const* d_in, const int* in_sizes, int n_in,
                              void* d_out, int out_size, void* d_ws, size_t ws_size,
                              hipStream_t stream)
{
  const float* tgt  = (const float*)d_in[0];
  const float* memi = (const float*)d_in[1];
  const int*   mask = (const int*)d_in[2];
  const float* sa_wq = (const float*)d_in[3];  const float* sa_bq = (const float*)d_in[4];
  const float* sa_wk = (const float*)d_in[5];  const float* sa_bk = (const float*)d_in[6];
  const float* sa_wv = (const float*)d_in[7];  const float* sa_bv = (const float*)d_in[8];
  const float* sa_wo = (const float*)d_in[9];  const float* sa_bo = (const float*)d_in[10];
  const float* ca_wq = (const float*)d_in[11]; const float* ca_bq = (const float*)d_in[12];
  const float* ca_wk = (const float*)d_in[13]; const float* ca_bk = (const float*)d_in[14];
  const float* ca_wv = (const float*)d_in[15]; const float* ca_bv = (const float*)d_in[16];
  const float* ca_wo = (const float*)d_in[17]; const float* ca_bo = (const float*)d_in[18];
  const float* w1 = (const float*)d_in[19]; const float* b1 = (const float*)d_in[20];
  const float* w2 = (const float*)d_in[21]; const float* b2 = (const float*)d_in[22];
  const float* g1 = (const float*)d_in[23]; const float* be1 = (const float*)d_in[24];
  const float* g2 = (const float*)d_in[25]; const float* be2 = (const float*)d_in[26];
  const float* g3 = (const float*)d_in[27]; const float* be3 = (const float*)d_in[28];
  float* out = (float*)d_out;
  char* W = (char*)d_ws;
  const size_t MB = 1 << 20;
  typedef unsigned short us;
  const float QSCALE = 0.18033688011112042f;   // 0.125 * log2(e)

  // workspace layout (byte offsets; total ~106 MB).
  // NOTE: QKV spans 49-73MB, so T1b lives at 98MB (NOT inside 49-73).
  us* Wsaqkv = (us*)(W + 0);          // [3072][1024] bf16
  us* Wsao   = (us*)(W + 6 * MB);
  us* Wcaqkv = (us*)(W + 8 * MB);     // [3072][1024] = Wcaq | Wcakv contiguous
  us* Wcao   = (us*)(W + 14 * MB);
  us* W1t    = (us*)(W + 16 * MB);    // [4096][1024]
  us* W2t    = (us*)(W + 24 * MB);    // [1024][4096]
  float* b_saqkv = (float*)(W + 32 * MB);
  float* b_caqkv = (float*)(W + 32 * MB + 16384);
  us* tgt_bf = (us*)(W + 33 * MB);    // read by addln#1; then reused as T2b
  us* T2b    = tgt_bf;
  us* mem_bf = (us*)(W + 41 * MB);
  us* QKV    = (us*)(W + 49 * MB);    // [4096][3072] = 49-73MB (SA and CA reuse)
  us* AO     = (us*)(W + 73 * MB);    // [4096][1024] bf16, 73-81
  us* Hb     = (us*)(W + 49 * MB);    // FFN hidden [4096][4096] bf16 (49-81; QKV/AO dead)
  us* Opb    = (us*)(W + 81 * MB);    // TWO [4096][1024] bf16 partial slabs (81-97)
  us* mpack  = (us*)(W + 97 * MB);    // [4][8][16][512] ushort bitmasks, 512KB
  us* T1b    = (us*)(W + 98 * MB);    // [4096][1024] bf16, 98-106 (clear of QKV!)
  us* Opb1   = Opb + 4096 * 1024;

  const int M = 4096;
  dim3 blk(256);
  auto gemm = [&](const us* Aa, const us* Aa2, int nsplit, const us* Bta,
                  const float* bias, void* Cc, int Nn, int Kk, int flags, int zsplit) {
    gemm_bf16_kernel<<<dim3(Nn / 128, M / 128, zsplit), blk, 0, stream>>>(
        Aa, Aa2, nsplit, Bta, bias, Cc, M, Nn, Kk, flags);
  };

  // ---- prep ----
  TPtrs tp;
  tp.s[0] = sa_wq; tp.d[0] = Wsaqkv;               tp.scale[0] = QSCALE;
  tp.s[1] = sa_wk; tp.d[1] = Wsaqkv + 1024 * 1024; tp.scale[1] = 1.f;
  tp.s[2] = sa_wv; tp.d[2] = Wsaqkv + 2048 * 1024; tp.scale[2] = 1.f;
  tp.s[3] = sa_wo; tp.d[3] = Wsao;                 tp.scale[3] = 1.f;
  tp.s[4] = ca_wq; tp.d[4] = Wcaqkv;               tp.scale[4] = QSCALE;
  tp.s[5] = ca_wk; tp.d[5] = Wcaqkv + 1024 * 1024; tp.scale[5] = 1.f;
  tp.s[6] = ca_wv; tp.d[6] = Wcaqkv + 2048 * 1024; tp.scale[6] = 1.f;
  tp.s[7] = ca_wo; tp.d[7] = Wcao;                 tp.scale[7] = 1.f;
  tcvt_batch_kernel<<<dim3(32, 32, 8), blk, 0, stream>>>(tp);
  transpose_cvt_kernel<<<dim3(128, 32), blk, 0, stream>>>(w1, W1t, 1024, 4096);
  transpose_cvt_kernel<<<dim3(32, 128), blk, 0, stream>>>(w2, W2t, 4096, 1024);
  cvt2_bf16_kernel<<<dim3(4096), blk, 0, stream>>>(tgt, memi, tgt_bf, mem_bf, M * 1024 / 8);
  biasprep_kernel<<<dim3(12), blk, 0, stream>>>(sa_bq, sa_bk, sa_bv, ca_bq, ca_bk, ca_bv,
                                                b_saqkv, b_caqkv, QSCALE);
  maskprep_kernel<<<dim3(1024), blk, 0, stream>>>(mask, mpack);

  // ---- self-attention ----
  gemm(tgt_bf, tgt_bf, 1 << 30, Wsaqkv, b_saqkv, QKV, 3072, 1024, 2, 1);
  attn_kernel<<<dim3(8, 16, 4), dim3(512), 0, stream>>>(QKV, QKV + 1024, QKV + 2048, 3072, 3072, mpack, AO);
  gemm(AO, AO, 1 << 30, Wsao, sa_bo, Opb, 1024, 1024, 2, 2);   // split-K=2
  addln_kernel<<<dim3(M), blk, 0, stream>>>(tgt_bf, Opb, Opb1, g1, be1, T1b, nullptr);

  // ---- cross-attention (Q from T1b, K/V from mem_bf; one merged GEMM) ----
  gemm(T1b, mem_bf, 8, Wcaqkv, b_caqkv, QKV, 3072, 1024, 2, 1);
  attn_kernel<<<dim3(8, 16, 4), dim3(512), 0, stream>>>(QKV, QKV + 1024, QKV + 2048, 3072, 3072, mpack, AO);
  gemm(AO, AO, 1 << 30, Wcao, ca_bo, Opb, 1024, 1024, 2, 2);   // split-K=2
  addln_kernel<<<dim3(M), blk, 0, stream>>>(T1b, Opb, Opb1, g2, be2, T2b, nullptr);

  // ---- FFN ----
  gemm(T2b, T2b, 1 << 30, W1t, b1, Hb, 4096, 1024, 3, 1);
  gemm(Hb, Hb, 1 << 30, W2t, b2, Opb, 1024, 4096, 2, 2);       // split-K=2
  addln_kernel<<<dim3(M), blk, 0, stream>>>(T2b, Opb, Opb1, g3, be3, nullptr, out);

  (void)in_sizes; (void)n_in; (void)out_size; (void)ws_size;
}

// Round 19
// 379.236 us; speedup vs baseline: 1.0141x; 1.0004x over previous
//
#include <hip/hip_runtime.h>
#include <math.h>

typedef float f32x4 __attribute__((ext_vector_type(4)));
typedef unsigned short ushort8 __attribute__((ext_vector_type(8)));
typedef unsigned short ushort4v __attribute__((ext_vector_type(4)));
typedef __bf16 bf16x8 __attribute__((ext_vector_type(8)));
typedef unsigned int u32;

__device__ __forceinline__ unsigned short f2bf(float x) {
  union { float f; unsigned u; } v; v.f = x;
  unsigned r = v.u + 0x7FFFu + ((v.u >> 16) & 1u);   // RNE
  return (unsigned short)(r >> 16);
}
__device__ __forceinline__ float bf2f(unsigned short u) {
  union { unsigned u; float f; } c; c.u = ((unsigned)u) << 16; return c.f;
}

__device__ __forceinline__ f32x4 mfma16(ushort8 a, ushort8 b, f32x4 c) {
  return __builtin_amdgcn_mfma_f32_16x16x32_bf16(
      __builtin_bit_cast(bf16x8, a), __builtin_bit_cast(bf16x8, b), c, 0, 0, 0);
}

// async global->LDS, 16B per lane; LDS dest = wave-uniform base, HW adds lane*16
__device__ __forceinline__ void gload16(const void* g, void* l) {
  __builtin_amdgcn_global_load_lds((const __attribute__((address_space(1))) u32*)g,
                                   (__attribute__((address_space(3))) u32*)l, 16, 0, 0);
}

// bijective XCD swizzle (m204): contiguous chunk of linear ids per XCD
__device__ __forceinline__ int xcd_swz(int orig, int nwg) {
  int q = nwg >> 3, r = nwg & 7;
  int xcd = orig & 7, lid = orig >> 3;
  return (xcd < r ? xcd * (q + 1) : r * (q + 1) + (xcd - r) * q) + lid;
}

// ---------------------------------------------------------------------------
// bf16 GEMM: C[M,N] = A[M,K] @ Bt[N,K]^T + bias. 128x128, BK=64.
// Depth-2 counted-vmcnt pipeline + XCD swizzle. Split-K via gridDim.z
// (slice z -> C + z*M*N, bias only z==0). Per-block A select: blocks with
// bn < nsplit read A, others A2 (for merged multi-source GEMMs).
// flags: 1 = relu, 2 = bf16 out
// ---------------------------------------------------------------------------
__global__ __launch_bounds__(256) void gemm_bf16_kernel(
    const unsigned short* __restrict__ A, const unsigned short* __restrict__ A2,
    int nsplit, const unsigned short* __restrict__ Bt,
    const float* __restrict__ bias, void* __restrict__ C,
    int M, int N, int K, int flags)
{
  __shared__ __align__(16) char As0[128 * 128];
  __shared__ __align__(16) char Bs0[128 * 128];
  __shared__ __align__(16) char As1[128 * 128];
  __shared__ __align__(16) char Bs1[128 * 128];
  const int gx = gridDim.x;
  const int wg = xcd_swz(blockIdx.x + gx * blockIdx.y, gx * gridDim.y);
  const int bn = wg % gx, bm = wg / gx;
  const int z = blockIdx.z;
  const int t = threadIdx.x;
  const int lane = t & 63, w = t >> 6, wm = w >> 1, wn = w & 1;
  const int l4 = lane & 15, lg = lane >> 4;
  const size_t K2 = (size_t)K * 2;

  f32x4 acc[4][4];
#pragma unroll
  for (int i = 0; i < 4; ++i)
#pragma unroll
    for (int j = 0; j < 4; ++j) acc[i][j] = f32x4{0.f, 0.f, 0.f, 0.f};

  const int lr = lane >> 3;
  const int ls = (lane & 7) ^ lr;
  const unsigned short* Ause = (bn < nsplit) ? A : A2;
  const char* Ag = (const char*)Ause + (size_t)(bm * 128 + w * 32 + lr) * K2 + ls * 16;
  const char* Bg = (const char*)Bt + (size_t)(bn * 128 + w * 32 + lr) * K2 + ls * 16;
  const int wo = w * 4096;

  auto STAGE = [&](char* Al, char* Bl, int kt) {
    const size_t ko = (size_t)kt * 128;
#pragma unroll
    for (int i = 0; i < 4; ++i) {
      gload16(Ag + i * 8 * K2 + ko, Al + wo + i * 1024);
      gload16(Bg + i * 8 * K2 + ko, Bl + wo + i * 1024);
    }
  };
  auto COMPUTE = [&](const char* As, const char* Bs) {
#pragma unroll
    for (int ks = 0; ks < 2; ++ks) {
      const int kb = ks * 64 + lg * 16;
      ushort8 af[4], bfr[4];
#pragma unroll
      for (int mi = 0; mi < 4; ++mi) {
        int r = wm * 64 + mi * 16 + l4;
        af[mi] = *reinterpret_cast<const ushort8*>(As + r * 128 + (kb ^ ((r & 7) << 4)));
      }
#pragma unroll
      for (int ni = 0; ni < 4; ++ni) {
        int r = wn * 64 + ni * 16 + l4;
        bfr[ni] = *reinterpret_cast<const ushort8*>(Bs + r * 128 + (kb ^ ((r & 7) << 4)));
      }
#pragma unroll
      for (int mi = 0; mi < 4; ++mi)
#pragma unroll
        for (int ni = 0; ni < 4; ++ni)
          acc[mi][ni] = mfma16(af[mi], bfr[ni], acc[mi][ni]);
    }
  };

#define GWAIT(more) do { if (more) asm volatile("s_waitcnt vmcnt(8)" ::: "memory"); \
                         else      asm volatile("s_waitcnt vmcnt(0)" ::: "memory"); } while (0)

  const int nkt2 = (K >> 6) / gridDim.z;   // even
  const int kbeg = z * nkt2, kend = kbeg + nkt2;
  STAGE(As0, Bs0, kbeg);
  STAGE(As1, Bs1, kbeg + 1);   // 16 loads/wave in flight
  for (int kt = kbeg; kt < kend; kt += 2) {
    GWAIT(kt + 1 < kend);
    __builtin_amdgcn_s_barrier();
    __builtin_amdgcn_sched_barrier(0);
    COMPUTE(As0, Bs0);
    __builtin_amdgcn_s_barrier();
    __builtin_amdgcn_sched_barrier(0);
    if (kt + 2 < kend) STAGE(As0, Bs0, kt + 2);
    GWAIT(kt + 2 < kend);
    __builtin_amdgcn_s_barrier();
    __builtin_amdgcn_sched_barrier(0);
    COMPUTE(As1, Bs1);
    __builtin_amdgcn_s_barrier();
    __builtin_amdgcn_sched_barrier(0);
    if (kt + 3 < kend) STAGE(As1, Bs1, kt + 3);
  }
#undef GWAIT

  const int relu = flags & 1, obf = flags & 2;
#pragma unroll
  for (int mi = 0; mi < 4; ++mi)
#pragma unroll
    for (int ni = 0; ni < 4; ++ni) {
      int col = bn * 128 + wn * 64 + ni * 16 + l4;
      float bia = (z == 0) ? bias[col] : 0.f;
#pragma unroll
      for (int j = 0; j < 4; ++j) {
        int row = bm * 128 + wm * 64 + mi * 16 + lg * 4 + j;
        float vv = acc[mi][ni][j] + bia;
        if (relu) vv = fmaxf(vv, 0.f);
        size_t idx = (size_t)z * M * N + (size_t)row * N + col;
        if (obf) ((unsigned short*)C)[idx] = f2bf(vv);
        else     ((float*)C)[idx] = vv;
      }
    }
}

// ---------------------------------------------------------------------------
// Flash attention, bf16, log2-domain softmax (Q pre-scaled by 0.125*log2e).
// QBLK=128: block = (qt, h, b) XCD-swizzled, 512 threads = 8 waves x 16
// q-rows. V swizzle carries an extra ((row>>3)&1)<<4 XOR term (bank bit 2
// from lane&1) making the transpose write conflict-free (was 4-way); the
// same term is applied on the PV read (both-sides rule; term is a pure
// row function with no bits below bit 4, so 16B reads stay contiguous).
// Round-14 tile schedule: V-write pre-barrier, single barrier/tile, PV
// in-tile after lgkmcnt(0); trigger-gated max; l via MFMA-ones.
// ---------------------------------------------------------------------------
constexpr int kS = 1024, kD = 1024, kDH = 64;

__global__ __launch_bounds__(512) void attn_kernel(
    const unsigned short* __restrict__ Qg, const unsigned short* __restrict__ Kg,
    const unsigned short* __restrict__ Vg, int qs, int ks_,
    const unsigned short* __restrict__ mpack, unsigned short* __restrict__ Og)
{
  __shared__ __align__(16) char Ks0[8192];
  __shared__ __align__(16) char Ks1[8192];
  __shared__ __align__(16) char VT0[8192];
  __shared__ __align__(16) char VT1[8192];
  __shared__ __align__(16) char Ps[16384];
  const int wg = xcd_swz(blockIdx.x + 8 * (blockIdx.y + 16 * blockIdx.z), 512);
  const int qt = wg & 7, h = (wg >> 3) & 15, b = wg >> 7;
  const int t = threadIdx.x, lane = t & 63, w = t >> 6;   // w in 0..7
  const int l4 = lane & 15, lg = lane >> 4;
  const int lr = lane >> 3, sg = (lane & 7) ^ lr;

  // Q in registers: A-frag row = l4 (wave-local q-row), k = ks*32 + lg*8 + i
  ushort8 q0, q1;
  {
    const unsigned short* src = Qg + (size_t)(b * kS + qt * 128 + w * 16 + l4) * qs + h * kDH;
    q0 = *reinterpret_cast<const ushort8*>(src + lg * 8);
    q1 = *reinterpret_cast<const ushort8*>(src + 32 + lg * 8);
  }
  ushort8 onesv;
#pragma unroll
  for (int i = 0; i < 8; ++i) onesv[i] = 0x3F80;   // bf16 1.0

  // per-thread bitmask base: mpack[((b*8+qt)*16+kt)*512 + t]
  const unsigned short* mtb = mpack + (size_t)(b * 8 + qt) * 8192 + t;

  // K tile: wave w stages rows w*8..w*8+7 (1KB); LDS row r slot s holds cols
  // (s^(r&7))*8..+7 (read: kb ^ ((r&7)<<4)) -- r&7 == lane>>3 within wave
  auto stageK = [&](char* Kl, int kt) {
    const char* base = (const char*)(Kg + (size_t)(b * kS + kt * 64) * ks_ + h * kDH) + sg * 16;
    gload16(base + (size_t)(w * 8 + lr) * (ks_ * 2), Kl + w * 1024);
  };

  float m_r[4];
  f32x4 l_acc = f32x4{0.f, 0.f, 0.f, 0.f};
  f32x4 o[4];
#pragma unroll
  for (int j = 0; j < 4; ++j) m_r[j] = -1e30f;
#pragma unroll
  for (int di = 0; di < 4; ++di) o[di] = f32x4{0.f, 0.f, 0.f, 0.f};

  // V prefetch: thread t covers V[key = t>>3][c0 = (t&7)*8 .. +7] (16B)
  ushort8 vA, vB;
  unsigned short mA, mB;
  stageK(Ks0, 0);
  {
    const unsigned short* vsrc = Vg + (size_t)(b * kS + (t >> 3)) * ks_ + h * kDH + (t & 7) * 8;
    vA = *reinterpret_cast<const ushort8*>(vsrc);
    mA = mtb[0];
  }

#define ATTN_TILE(KC, VC, KN, VCC, VNN, MCUR, MNXT, KTV)                                 \
  {                                                                                      \
    asm volatile("s_waitcnt vmcnt(0)" ::: "memory");                                     \
    { /* V(k) transpose write into VC BEFORE the barrier (conflict-free swizzle) */      \
      int key2 = (t >> 3) * 2, c0 = (t & 7) * 8;                                         \
      _Pragma("unroll")                                                                  \
      for (int i = 0; i < 8; ++i) {                                                      \
        int dh = c0 + i;                                                                 \
        *(unsigned short*)(VC + dh * 128 +                                               \
            (key2 ^ ((dh & 7) << 4) ^ ((dh >> 4) << 5) ^ (((dh >> 3) & 1) << 4)))        \
            = VCC[i];                                                                    \
      }                                                                                  \
    }                                                                                    \
    asm volatile("s_waitcnt lgkmcnt(0)" ::: "memory");                                   \
    __builtin_amdgcn_s_barrier();                                                        \
    __builtin_amdgcn_sched_barrier(0);                                                   \
    if ((KTV) + 1 < 16) { /* prefetch next tile (flies under compute) */                 \
      stageK(KN, (KTV) + 1);                                                             \
      const unsigned short* vsrc = Vg +                                                  \
          (size_t)(b * kS + ((KTV) + 1) * 64 + (t >> 3)) * ks_ + h * kDH + (t & 7) * 8;  \
      VNN = *reinterpret_cast<const ushort8*>(vsrc);                                     \
      MNXT = mtb[((KTV) + 1) * 512];                                                     \
    }                                                                                    \
    f32x4 sc[4];                                                                         \
    _Pragma("unroll")                                                                    \
    for (int ni = 0; ni < 4; ++ni) sc[ni] = f32x4{0.f, 0.f, 0.f, 0.f};                   \
    __builtin_amdgcn_s_setprio(1);                                                       \
    _Pragma("unroll")                                                                    \
    for (int ks = 0; ks < 2; ++ks) {                                                     \
      const int kb = ks * 64 + lg * 16;                                                  \
      ushort8 a = ks ? q1 : q0;                                                          \
      _Pragma("unroll")                                                                  \
      for (int ni = 0; ni < 4; ++ni) {                                                   \
        int kr = ni * 16 + l4;                                                           \
        ushort8 bb = *(const ushort8*)(KC + kr * 128 + (kb ^ ((kr & 7) << 4)));          \
        sc[ni] = mfma16(a, bb, sc[ni]);                                                  \
      }                                                                                  \
    }                                                                                    \
    __builtin_amdgcn_s_setprio(0);                                                       \
    const unsigned mbits_ = (unsigned)(MCUR);                                            \
    float tmax[4];                                                                       \
    _Pragma("unroll")                                                                    \
    for (int j = 0; j < 4; ++j) {                                                        \
      _Pragma("unroll")                                                                  \
      for (int ni = 0; ni < 4; ++ni)                                                     \
        if (!((mbits_ >> (ni * 4 + j)) & 1u)) sc[ni][j] = -1e9f;                         \
      tmax[j] = fmaxf(fmaxf(sc[0][j], sc[1][j]), fmaxf(sc[2][j], sc[3][j]));             \
    }                                                                                    \
    bool need = (tmax[0] > m_r[0] + 8.f) || (tmax[1] > m_r[1] + 8.f) ||                  \
                (tmax[2] > m_r[2] + 8.f) || (tmax[3] > m_r[3] + 8.f);                    \
    if (__any(need)) { /* rare after first tile: full reduce + rescale */                \
      _Pragma("unroll")                                                                  \
      for (int j = 0; j < 4; ++j) {                                                      \
        tmax[j] = fmaxf(tmax[j], __shfl_xor(tmax[j], 1, 64));                            \
        tmax[j] = fmaxf(tmax[j], __shfl_xor(tmax[j], 2, 64));                            \
        tmax[j] = fmaxf(tmax[j], __shfl_xor(tmax[j], 4, 64));                            \
        tmax[j] = fmaxf(tmax[j], __shfl_xor(tmax[j], 8, 64));                            \
        float mn = fmaxf(m_r[j], tmax[j]);                                               \
        float al = exp2f(m_r[j] - mn);                                                   \
        m_r[j] = mn;                                                                     \
        o[0][j] *= al; o[1][j] *= al; o[2][j] *= al; o[3][j] *= al;                      \
        l_acc[j] *= al;                                                                  \
      }                                                                                  \
    }                                                                                    \
    _Pragma("unroll")                                                                    \
    for (int ni = 0; ni < 4; ++ni)                                                       \
      _Pragma("unroll")                                                                  \
      for (int j = 0; j < 4; ++j)                                                        \
        sc[ni][j] = exp2f(sc[ni][j] - m_r[j]);                                           \
    { /* P -> per-wave LDS region, conflict-free swizzle */                              \
      char* Pw = Ps + w * 2048;                                                          \
      _Pragma("unroll")                                                                  \
      for (int ni = 0; ni < 4; ++ni)                                                     \
        _Pragma("unroll")                                                                \
        for (int j = 0; j < 4; ++j) {                                                    \
          int row = lg * 4 + j, col = ni * 16 + l4;                                      \
          *(unsigned short*)(Pw + row * 128 +                                            \
              ((col * 2) ^ ((row & 7) << 4) ^ ((row & 8) << 2))) =                       \
              __builtin_bit_cast(unsigned short, (__bf16)sc[ni][j]);                     \
        }                                                                                \
    }                                                                                    \
    asm volatile("s_waitcnt lgkmcnt(0)" ::: "memory");                                   \
    __builtin_amdgcn_sched_barrier(0);                                                   \
    __builtin_amdgcn_s_setprio(1);                                                       \
    { /* PV + l-accumulation via ones-MFMA */                                            \
      const char* Pw = Ps + w * 2048;                                                    \
      _Pragma("unroll")                                                                  \
      for (int ks = 0; ks < 2; ++ks) {                                                   \
        const int kb = ks * 64 + lg * 16;                                                \
        ushort8 pa = *(const ushort8*)(Pw + l4 * 128 +                                   \
            (kb ^ ((l4 & 7) << 4) ^ ((l4 & 8) << 2)));                                   \
        l_acc = mfma16(pa, onesv, l_acc);                                                \
        _Pragma("unroll")                                                                \
        for (int di = 0; di < 4; ++di) {                                                 \
          int vr2 = di * 16 + l4;                                                        \
          ushort8 vb = *(const ushort8*)(VC + vr2 * 128 +                                \
              (kb ^ ((vr2 & 7) << 4) ^ ((vr2 >> 4) << 5) ^ (((vr2 >> 3) & 1) << 4)));    \
          o[di] = mfma16(pa, vb, o[di]);                                                 \
        }                                                                                \
      }                                                                                  \
    }                                                                                    \
    __builtin_amdgcn_s_setprio(0);                                                       \
  }

  for (int kt = 0; kt < 16; kt += 2) {
    ATTN_TILE(Ks0, VT0, Ks1, vA, vB, mA, mB, kt);
    ATTN_TILE(Ks1, VT1, Ks0, vB, vA, mB, mA, kt + 1);
  }
#undef ATTN_TILE

  // epilogue: l_acc[j] already holds the full row sum for q = lg*4+j
  float rinv[4];
#pragma unroll
  for (int j = 0; j < 4; ++j) rinv[j] = 1.0f / l_acc[j];
#pragma unroll
  for (int di = 0; di < 4; ++di) {
    int col = h * kDH + di * 16 + l4;
#pragma unroll
    for (int j = 0; j < 4; ++j) {
      int qrow = qt * 128 + w * 16 + lg * 4 + j;
      Og[(size_t)(b * kS + qrow) * kD + col] =
          __builtin_bit_cast(unsigned short, (__bf16)(o[di][j] * rinv[j]));
    }
  }
}

// ---------------------------------------------------------------------------
// out = LayerNorm(x + y0 + y1) * g + be (D=1024); all bf16 inputs; bf16 out
// and/or f32 out (either pointer may be null).
// ---------------------------------------------------------------------------
__global__ __launch_bounds__(256) void addln_kernel(
    const unsigned short* __restrict__ x, const unsigned short* __restrict__ y0,
    const unsigned short* __restrict__ y1,
    const float* __restrict__ g, const float* __restrict__ be,
    unsigned short* __restrict__ outb, float* __restrict__ outf)
{
  const int row = blockIdx.x, t = threadIdx.x;
  const size_t base = (size_t)row * 1024 + t * 4;
  ushort4v xv = *reinterpret_cast<const ushort4v*>(x + base);
  ushort4v yv0 = *reinterpret_cast<const ushort4v*>(y0 + base);
  ushort4v yv1 = *reinterpret_cast<const ushort4v*>(y1 + base);
  float v0 = bf2f(xv[0]) + bf2f(yv0[0]) + bf2f(yv1[0]);
  float v1 = bf2f(xv[1]) + bf2f(yv0[1]) + bf2f(yv1[1]);
  float v2 = bf2f(xv[2]) + bf2f(yv0[2]) + bf2f(yv1[2]);
  float v3 = bf2f(xv[3]) + bf2f(yv0[3]) + bf2f(yv1[3]);
  float s1 = v0 + v1 + v2 + v3;
  float s2 = v0 * v0 + v1 * v1 + v2 * v2 + v3 * v3;
#pragma unroll
  for (int off = 1; off < 64; off <<= 1) {
    s1 += __shfl_xor(s1, off, 64);
    s2 += __shfl_xor(s2, off, 64);
  }
  __shared__ float r1[4], r2[4];
  const int w = t >> 6, lane = t & 63;
  if (lane == 0) { r1[w] = s1; r2[w] = s2; }
  __syncthreads();
  s1 = r1[0] + r1[1] + r1[2] + r1[3];
  s2 = r2[0] + r2[1] + r2[2] + r2[3];
  const float mean = s1 * (1.0f / 1024.0f);
  const float var = s2 * (1.0f / 1024.0f) - mean * mean;
  const float rs = rsqrtf(var + 1e-5f);
  float4 gv = *reinterpret_cast<const float4*>(g + t * 4);
  float4 bv = *reinterpret_cast<const float4*>(be + t * 4);
  float4 ov;
  ov.x = (v0 - mean) * rs * gv.x + bv.x;
  ov.y = (v1 - mean) * rs * gv.y + bv.y;
  ov.z = (v2 - mean) * rs * gv.z + bv.z;
  ov.w = (v3 - mean) * rs * gv.w + bv.w;
  if (outb) {
    ushort4v bo;
    bo[0] = f2bf(ov.x); bo[1] = f2bf(ov.y); bo[2] = f2bf(ov.z); bo[3] = f2bf(ov.w);
    *reinterpret_cast<ushort4v*>(outb + base) = bo;
  }
  if (outf) *reinterpret_cast<float4*>(outf + base) = ov;
}

// ---------------------------------------------------------------------------
__global__ __launch_bounds__(256) void cvt2_bf16_kernel(
    const float* __restrict__ a, const float* __restrict__ b,
    unsigned short* __restrict__ da, unsigned short* __restrict__ db, int n8each)
{
  int i = blockIdx.x * 256 + threadIdx.x;
  const float* s = a; unsigned short* d = da;
  if (i >= n8each) { s = b; d = db; i -= n8each; }
  if (i >= n8each) return;
  float4 f0 = reinterpret_cast<const float4*>(s)[i * 2];
  float4 f1 = reinterpret_cast<const float4*>(s)[i * 2 + 1];
  ushort8 v;
  v[0] = f2bf(f0.x); v[1] = f2bf(f0.y); v[2] = f2bf(f0.z); v[3] = f2bf(f0.w);
  v[4] = f2bf(f1.x); v[5] = f2bf(f1.y); v[6] = f2bf(f1.z); v[7] = f2bf(f1.w);
  reinterpret_cast<ushort8*>(d)[i] = v;
}

// W[K][N] f32 -> Wt[n][k] bf16 (dst stride = K)
__global__ __launch_bounds__(256) void transpose_cvt_kernel(
    const float* __restrict__ src, unsigned short* __restrict__ dst, int K, int N)
{
  __shared__ float tile[32][33];
  const int bx = blockIdx.x, by = blockIdx.y;
  const int tx = threadIdx.x & 31, ty = threadIdx.x >> 5;
#pragma unroll
  for (int i = 0; i < 4; ++i)
    tile[ty + i * 8][tx] = src[(size_t)(by * 32 + ty + i * 8) * N + bx * 32 + tx];
  __syncthreads();
#pragma unroll
  for (int i = 0; i < 4; ++i)
    dst[(size_t)(bx * 32 + ty + i * 8) * K + by * 32 + tx] = f2bf(tile[tx][ty + i * 8]);
}

// batched 1024x1024 transposes with per-entry scale, grid (32,32,8)
struct TPtrs { const float* s[8]; unsigned short* d[8]; float scale[8]; };
__global__ __launch_bounds__(256) void tcvt_batch_kernel(TPtrs p)
{
  __shared__ float tile[32][33];
  const float* __restrict__ src = p.s[blockIdx.z];
  unsigned short* __restrict__ dst = p.d[blockIdx.z];
  const float sc = p.scale[blockIdx.z];
  const int bx = blockIdx.x, by = blockIdx.y;
  const int tx = threadIdx.x & 31, ty = threadIdx.x >> 5;
#pragma unroll
  for (int i = 0; i < 4; ++i)
    tile[ty + i * 8][tx] = src[(size_t)(by * 32 + ty + i * 8) * 1024 + bx * 32 + tx];
  __syncthreads();
#pragma unroll
  for (int i = 0; i < 4; ++i)
    dst[(size_t)(bx * 32 + ty + i * 8) * 1024 + by * 32 + tx] = f2bf(tile[tx][ty + i * 8] * sc);
}

__global__ void biasprep_kernel(const float* sq, const float* sk, const float* sv,
                                const float* cq, const float* ck, const float* cv,
                                float* bsa, float* bca, float s)
{
  int i = blockIdx.x * 256 + threadIdx.x;
  if (i < 1024)      { bsa[i] = sq[i] * s;        bca[i] = cq[i] * s; }
  else if (i < 2048) { bsa[i] = sk[i - 1024];     bca[i] = ck[i - 1024]; }
  else if (i < 3072) { bsa[i] = sv[i - 2048];     bca[i] = cv[i - 2048]; }
}

// mask int32 -> per-attn-thread 16-bit bitmask (512-thread blocks):
// mpack[((b*8+qt)*16+kt)*512 + t], bit (ni*4+j) = mask for
// q = qt*128 + ((t>>6)&7)*16 + ((t>>4)&3)*4 + j,  k = kt*64 + ni*16 + (t&15)
__global__ __launch_bounds__(256) void maskprep_kernel(
    const int* __restrict__ mask, unsigned short* __restrict__ mpack)
{
  int idx = blockIdx.x * 256 + threadIdx.x;   // 262144 slots
  int t = idx & 511;
  int kt = (idx >> 9) & 15;
  int qt = (idx >> 13) & 7;
  int b = idx >> 16;
  int qb = qt * 128 + ((t >> 6) & 7) * 16 + ((t >> 4) & 3) * 4;
  int kb = kt * 64 + (t & 15);
  unsigned m = 0;
#pragma unroll
  for (int ni = 0; ni < 4; ++ni)
#pragma unroll
    for (int j = 0; j < 4; ++j)
      if (mask[(size_t)(b * 1024 + qb + j) * 1024 + kb + ni * 16]) m |= 1u << (ni * 4 + j);
  mpack[idx] = (unsigned short)m;
}

// ---------------------------------------------------------------------------
extern "C" void kernel_launch(void* const* d_in, const int* in_sizes, int n_in,
                              void* d_out, int out_size, void* d_ws, size_t ws_size,
                              hipStream_t stream)
{
  const float* tgt  = (const float*)d_in[0];
  const float* memi = (const float*)d_in[1];
  const int*   mask = (const int*)d_in[2];
  const float* sa_wq = (const float*)d_in[3];  const float* sa_bq = (const float*)d_in[4];
  const float* sa_wk = (const float*)d_in[5];  const float* sa_bk = (const float*)d_in[6];
  const float* sa_wv = (const float*)d_in[7];  const float* sa_bv = (const float*)d_in[8];
  const float* sa_wo = (const float*)d_in[9];  const float* sa_bo = (const float*)d_in[10];
  const float* ca_wq = (const float*)d_in[11]; const float* ca_bq = (const float*)d_in[12];
  const float* ca_wk = (const float*)d_in[13]; const float* ca_bk = (const float*)d_in[14];
  const float* ca_wv = (const float*)d_in[15]; const float* ca_bv = (const float*)d_in[16];
  const float* ca_wo = (const float*)d_in[17]; const float* ca_bo = (const float*)d_in[18];
  const float* w1 = (const float*)d_in[19]; const float* b1 = (const float*)d_in[20];
  const float* w2 = (const float*)d_in[21]; const float* b2 = (const float*)d_in[22];
  const float* g1 = (const float*)d_in[23]; const float* be1 = (const float*)d_in[24];
  const float* g2 = (const float*)d_in[25]; const float* be2 = (const float*)d_in[26];
  const float* g3 = (const float*)d_in[27]; const float* be3 = (const float*)d_in[28];
  float* out = (float*)d_out;
  char* W = (char*)d_ws;
  const size_t MB = 1 << 20;
  typedef unsigned short us;
  const float QSCALE = 0.18033688011112042f;   // 0.125 * log2(e)

  // workspace layout (byte offsets; total ~106 MB).
  // NOTE: QKV spans 49-73MB, so T1b lives at 98MB (NOT inside 49-73).
  us* Wsaqkv = (us*)(W + 0);          // [3072][1024] bf16
  us* Wsao   = (us*)(W + 6 * MB);
  us* Wcaqkv = (us*)(W + 8 * MB);     // [3072][1024] = Wcaq | Wcakv contiguous
  us* Wcao   = (us*)(W + 14 * MB);
  us* W1t    = (us*)(W + 16 * MB);    // [4096][1024]
  us* W2t    = (us*)(W + 24 * MB);    // [1024][4096]
  float* b_saqkv = (float*)(W + 32 * MB);
  float* b_caqkv = (float*)(W + 32 * MB + 16384);
  us* tgt_bf = (us*)(W + 33 * MB);    // read by addln#1; then reused as T2b
  us* T2b    = tgt_bf;
  us* mem_bf = (us*)(W + 41 * MB);
  us* QKV    = (us*)(W + 49 * MB);    // [4096][3072] = 49-73MB (SA and CA reuse)
  us* AO     = (us*)(W + 73 * MB);    // [4096][1024] bf16, 73-81
  us* Hb     = (us*)(W + 49 * MB);    // FFN hidden [4096][4096] bf16 (49-81; QKV/AO dead)
  us* Opb    = (us*)(W + 81 * MB);    // TWO [4096][1024] bf16 partial slabs (81-97)
  us* mpack  = (us*)(W + 97 * MB);    // [4][8][16][512] ushort bitmasks, 512KB
  us* T1b    = (us*)(W + 98 * MB);    // [4096][1024] bf16, 98-106 (clear of QKV!)
  us* Opb1   = Opb + 4096 * 1024;

  const int M = 4096;
  dim3 blk(256);
  auto gemm = [&](const us* Aa, const us* Aa2, int nsplit, const us* Bta,
                  const float* bias, void* Cc, int Nn, int Kk, int flags, int zsplit) {
    gemm_bf16_kernel<<<dim3(Nn / 128, M / 128, zsplit), blk, 0, stream>>>(
        Aa, Aa2, nsplit, Bta, bias, Cc, M, Nn, Kk, flags);
  };

  // ---- prep ----
  TPtrs tp;
  tp.s[0] = sa_wq; tp.d[0] = Wsaqkv;               tp.scale[0] = QSCALE;
  tp.s[1] = sa_wk; tp.d[1] = Wsaqkv + 1024 * 1024; tp.scale[1] = 1.f;
  tp.s[2] = sa_wv; tp.d[2] = Wsaqkv + 2048 * 1024; tp.scale[2] = 1.f;
  tp.s[3] = sa_wo; tp.d[3] = Wsao;                 tp.scale[3] = 1.f;
  tp.s[4] = ca_wq; tp.d[4] = Wcaqkv;               tp.scale[4] = QSCALE;
  tp.s[5] = ca_wk; tp.d[5] = Wcaqkv + 1024 * 1024; tp.scale[5] = 1.f;
  tp.s[6] = ca_wv; tp.d[6] = Wcaqkv + 2048 * 1024; tp.scale[6] = 1.f;
  tp.s[7] = ca_wo; tp.d[7] = Wcao;                 tp.scale[7] = 1.f;
  tcvt_batch_kernel<<<dim3(32, 32, 8), blk, 0, stream>>>(tp);
  transpose_cvt_kernel<<<dim3(128, 32), blk, 0, stream>>>(w1, W1t, 1024, 4096);
  transpose_cvt_kernel<<<dim3(32, 128), blk, 0, stream>>>(w2, W2t, 4096, 1024);
  cvt2_bf16_kernel<<<dim3(4096), blk, 0, stream>>>(tgt, memi, tgt_bf, mem_bf, M * 1024 / 8);
  biasprep_kernel<<<dim3(12), blk, 0, stream>>>(sa_bq, sa_bk, sa_bv, ca_bq, ca_bk, ca_bv,
                                                b_saqkv, b_caqkv, QSCALE);
  maskprep_kernel<<<dim3(1024), blk, 0, stream>>>(mask, mpack);

  // ---- self-attention ----
  gemm(tgt_bf, tgt_bf, 1 << 30, Wsaqkv, b_saqkv, QKV, 3072, 1024, 2, 1);
  attn_kernel<<<dim3(8, 16, 4), dim3(512), 0, stream>>>(QKV, QKV + 1024, QKV + 2048, 3072, 3072, mpack, AO);
  gemm(AO, AO, 1 << 30, Wsao, sa_bo, Opb, 1024, 1024, 2, 2);   // split-K=2
  addln_kernel<<<dim3(M), blk, 0, stream>>>(tgt_bf, Opb, Opb1, g1, be1, T1b, nullptr);

  // ---- cross-attention (Q from T1b, K/V from mem_bf; one merged GEMM) ----
  gemm(T1b, mem_bf, 8, Wcaqkv, b_caqkv, QKV, 3072, 1024, 2, 1);
  attn_kernel<<<dim3(8, 16, 4), dim3(512), 0, stream>>>(QKV, QKV + 1024, QKV + 2048, 3072, 3072, mpack, AO);
  gemm(AO, AO, 1 << 30, Wcao, ca_bo, Opb, 1024, 1024, 2, 2);   // split-K=2
  addln_kernel<<<dim3(M), blk, 0, stream>>>(T1b, Opb, Opb1, g2, be2, T2b, nullptr);

  // ---- FFN ----
  gemm(T2b, T2b, 1 << 30, W1t, b1, Hb, 4096, 1024, 3, 1);
  gemm(Hb, Hb, 1 << 30, W2t, b2, Opb, 1024, 4096, 2, 2);       // split-K=2
  addln_kernel<<<dim3(M), blk, 0, stream>>>(T2b, Opb, Opb1, g3, be3, nullptr, out);

  (void)in_sizes; (void)n_in; (void)out_size; (void)ws_size;
}

// Round 20
// 378.406 us; speedup vs baseline: 1.0164x; 1.0022x over previous
//
#include <hip/hip_runtime.h>
#include <math.h>

typedef float f32x4 __attribute__((ext_vector_type(4)));
typedef unsigned short ushort8 __attribute__((ext_vector_type(8)));
typedef unsigned short ushort4v __attribute__((ext_vector_type(4)));
typedef __bf16 bf16x8 __attribute__((ext_vector_type(8)));
typedef unsigned int u32;

__device__ __forceinline__ unsigned short f2bf(float x) {
  union { float f; unsigned u; } v; v.f = x;
  unsigned r = v.u + 0x7FFFu + ((v.u >> 16) & 1u);   // RNE
  return (unsigned short)(r >> 16);
}
__device__ __forceinline__ float bf2f(unsigned short u) {
  union { unsigned u; float f; } c; c.u = ((unsigned)u) << 16; return c.f;
}

__device__ __forceinline__ f32x4 mfma16(ushort8 a, ushort8 b, f32x4 c) {
  return __builtin_amdgcn_mfma_f32_16x16x32_bf16(
      __builtin_bit_cast(bf16x8, a), __builtin_bit_cast(bf16x8, b), c, 0, 0, 0);
}

// async global->LDS, 16B per lane; LDS dest = wave-uniform base, HW adds lane*16
__device__ __forceinline__ void gload16(const void* g, void* l) {
  __builtin_amdgcn_global_load_lds((const __attribute__((address_space(1))) u32*)g,
                                   (__attribute__((address_space(3))) u32*)l, 16, 0, 0);
}

// bijective XCD swizzle (m204): contiguous chunk of linear ids per XCD
__device__ __forceinline__ int xcd_swz(int orig, int nwg) {
  int q = nwg >> 3, r = nwg & 7;
  int xcd = orig & 7, lid = orig >> 3;
  return (xcd < r ? xcd * (q + 1) : r * (q + 1) + (xcd - r) * q) + lid;
}

// ---------------------------------------------------------------------------
// bf16 GEMM: C[M,N] = A[M,K] @ Bt[N,K]^T + bias. 128x128, BK=64.
// Depth-2 counted-vmcnt pipeline + XCD swizzle. Split-K via gridDim.z
// (slice z -> C + z*M*N, bias only z==0). Per-block A select: blocks with
// bn < nsplit read A, others A2 (for merged multi-source GEMMs).
// flags: 1 = relu, 2 = bf16 out
// ---------------------------------------------------------------------------
__global__ __launch_bounds__(256) void gemm_bf16_kernel(
    const unsigned short* __restrict__ A, const unsigned short* __restrict__ A2,
    int nsplit, const unsigned short* __restrict__ Bt,
    const float* __restrict__ bias, void* __restrict__ C,
    int M, int N, int K, int flags)
{
  __shared__ __align__(16) char As0[128 * 128];
  __shared__ __align__(16) char Bs0[128 * 128];
  __shared__ __align__(16) char As1[128 * 128];
  __shared__ __align__(16) char Bs1[128 * 128];
  const int gx = gridDim.x;
  const int wg = xcd_swz(blockIdx.x + gx * blockIdx.y, gx * gridDim.y);
  const int bn = wg % gx, bm = wg / gx;
  const int z = blockIdx.z;
  const int t = threadIdx.x;
  const int lane = t & 63, w = t >> 6, wm = w >> 1, wn = w & 1;
  const int l4 = lane & 15, lg = lane >> 4;
  const size_t K2 = (size_t)K * 2;

  f32x4 acc[4][4];
#pragma unroll
  for (int i = 0; i < 4; ++i)
#pragma unroll
    for (int j = 0; j < 4; ++j) acc[i][j] = f32x4{0.f, 0.f, 0.f, 0.f};

  const int lr = lane >> 3;
  const int ls = (lane & 7) ^ lr;
  const unsigned short* Ause = (bn < nsplit) ? A : A2;
  const char* Ag = (const char*)Ause + (size_t)(bm * 128 + w * 32 + lr) * K2 + ls * 16;
  const char* Bg = (const char*)Bt + (size_t)(bn * 128 + w * 32 + lr) * K2 + ls * 16;
  const int wo = w * 4096;

  auto STAGE = [&](char* Al, char* Bl, int kt) {
    const size_t ko = (size_t)kt * 128;
#pragma unroll
    for (int i = 0; i < 4; ++i) {
      gload16(Ag + i * 8 * K2 + ko, Al + wo + i * 1024);
      gload16(Bg + i * 8 * K2 + ko, Bl + wo + i * 1024);
    }
  };
  auto COMPUTE = [&](const char* As, const char* Bs) {
#pragma unroll
    for (int ks = 0; ks < 2; ++ks) {
      const int kb = ks * 64 + lg * 16;
      ushort8 af[4], bfr[4];
#pragma unroll
      for (int mi = 0; mi < 4; ++mi) {
        int r = wm * 64 + mi * 16 + l4;
        af[mi] = *reinterpret_cast<const ushort8*>(As + r * 128 + (kb ^ ((r & 7) << 4)));
      }
#pragma unroll
      for (int ni = 0; ni < 4; ++ni) {
        int r = wn * 64 + ni * 16 + l4;
        bfr[ni] = *reinterpret_cast<const ushort8*>(Bs + r * 128 + (kb ^ ((r & 7) << 4)));
      }
#pragma unroll
      for (int mi = 0; mi < 4; ++mi)
#pragma unroll
        for (int ni = 0; ni < 4; ++ni)
          acc[mi][ni] = mfma16(af[mi], bfr[ni], acc[mi][ni]);
    }
  };

#define GWAIT(more) do { if (more) asm volatile("s_waitcnt vmcnt(8)" ::: "memory"); \
                         else      asm volatile("s_waitcnt vmcnt(0)" ::: "memory"); } while (0)

  const int nkt2 = (K >> 6) / gridDim.z;   // even
  const int kbeg = z * nkt2, kend = kbeg + nkt2;
  STAGE(As0, Bs0, kbeg);
  STAGE(As1, Bs1, kbeg + 1);   // 16 loads/wave in flight
  for (int kt = kbeg; kt < kend; kt += 2) {
    GWAIT(kt + 1 < kend);
    __builtin_amdgcn_s_barrier();
    __builtin_amdgcn_sched_barrier(0);
    COMPUTE(As0, Bs0);
    __builtin_amdgcn_s_barrier();
    __builtin_amdgcn_sched_barrier(0);
    if (kt + 2 < kend) STAGE(As0, Bs0, kt + 2);
    GWAIT(kt + 2 < kend);
    __builtin_amdgcn_s_barrier();
    __builtin_amdgcn_sched_barrier(0);
    COMPUTE(As1, Bs1);
    __builtin_amdgcn_s_barrier();
    __builtin_amdgcn_sched_barrier(0);
    if (kt + 3 < kend) STAGE(As1, Bs1, kt + 3);
  }
#undef GWAIT

  const int relu = flags & 1, obf = flags & 2;
#pragma unroll
  for (int mi = 0; mi < 4; ++mi)
#pragma unroll
    for (int ni = 0; ni < 4; ++ni) {
      int col = bn * 128 + wn * 64 + ni * 16 + l4;
      float bia = (z == 0) ? bias[col] : 0.f;
#pragma unroll
      for (int j = 0; j < 4; ++j) {
        int row = bm * 128 + wm * 64 + mi * 16 + lg * 4 + j;
        float vv = acc[mi][ni][j] + bia;
        if (relu) vv = fmaxf(vv, 0.f);
        size_t idx = (size_t)z * M * N + (size_t)row * N + col;
        if (obf) ((unsigned short*)C)[idx] = f2bf(vv);
        else     ((float*)C)[idx] = vv;
      }
    }
}

// ---------------------------------------------------------------------------
// Flash attention, bf16, log2-domain softmax (Q pre-scaled by 0.125*log2e).
// QBLK=128: block = (qt, h, b) XCD-swizzled, 512 threads = 8 waves x 16
// q-rows. Per-wave compute identical to the QBLK=64 version; staging split
// across 8 waves (stageK = 1 gload/wave; V = 1 ushort8/thread, 8 transpose
// writes). K/V tile amortized over 2x the q-rows. Round-14 tile schedule:
// V-write pre-barrier, single barrier/tile, PV in-tile after lgkmcnt(0);
// trigger-gated max; l via MFMA-ones. (Bank-conflict tuning closed: at this
// occupancy the ~1M conflicts are fully hidden -- round-19 A/B showed 2x
// conflicts with zero dur change.)
// ---------------------------------------------------------------------------
constexpr int kS = 1024, kD = 1024, kDH = 64;

__global__ __launch_bounds__(512) void attn_kernel(
    const unsigned short* __restrict__ Qg, const unsigned short* __restrict__ Kg,
    const unsigned short* __restrict__ Vg, int qs, int ks_,
    const unsigned short* __restrict__ mpack, unsigned short* __restrict__ Og)
{
  __shared__ __align__(16) char Ks0[8192];
  __shared__ __align__(16) char Ks1[8192];
  __shared__ __align__(16) char VT0[8192];
  __shared__ __align__(16) char VT1[8192];
  __shared__ __align__(16) char Ps[16384];
  const int wg = xcd_swz(blockIdx.x + 8 * (blockIdx.y + 16 * blockIdx.z), 512);
  const int qt = wg & 7, h = (wg >> 3) & 15, b = wg >> 7;
  const int t = threadIdx.x, lane = t & 63, w = t >> 6;   // w in 0..7
  const int l4 = lane & 15, lg = lane >> 4;
  const int lr = lane >> 3, sg = (lane & 7) ^ lr;

  // Q in registers: A-frag row = l4 (wave-local q-row), k = ks*32 + lg*8 + i
  ushort8 q0, q1;
  {
    const unsigned short* src = Qg + (size_t)(b * kS + qt * 128 + w * 16 + l4) * qs + h * kDH;
    q0 = *reinterpret_cast<const ushort8*>(src + lg * 8);
    q1 = *reinterpret_cast<const ushort8*>(src + 32 + lg * 8);
  }
  ushort8 onesv;
#pragma unroll
  for (int i = 0; i < 8; ++i) onesv[i] = 0x3F80;   // bf16 1.0

  // per-thread bitmask base: mpack[((b*8+qt)*16+kt)*512 + t]
  const unsigned short* mtb = mpack + (size_t)(b * 8 + qt) * 8192 + t;

  // K tile: wave w stages rows w*8..w*8+7 (1KB); LDS row r slot s holds cols
  // (s^(r&7))*8..+7 (read: kb ^ ((r&7)<<4)) -- r&7 == lane>>3 within wave
  auto stageK = [&](char* Kl, int kt) {
    const char* base = (const char*)(Kg + (size_t)(b * kS + kt * 64) * ks_ + h * kDH) + sg * 16;
    gload16(base + (size_t)(w * 8 + lr) * (ks_ * 2), Kl + w * 1024);
  };

  float m_r[4];
  f32x4 l_acc = f32x4{0.f, 0.f, 0.f, 0.f};
  f32x4 o[4];
#pragma unroll
  for (int j = 0; j < 4; ++j) m_r[j] = -1e30f;
#pragma unroll
  for (int di = 0; di < 4; ++di) o[di] = f32x4{0.f, 0.f, 0.f, 0.f};

  // V prefetch: thread t covers V[key = t>>3][c0 = (t&7)*8 .. +7] (16B)
  ushort8 vA, vB;
  unsigned short mA, mB;
  stageK(Ks0, 0);
  {
    const unsigned short* vsrc = Vg + (size_t)(b * kS + (t >> 3)) * ks_ + h * kDH + (t & 7) * 8;
    vA = *reinterpret_cast<const ushort8*>(vsrc);
    mA = mtb[0];
  }

#define ATTN_TILE(KC, VC, KN, VCC, VNN, MCUR, MNXT, KTV)                                 \
  {                                                                                      \
    asm volatile("s_waitcnt vmcnt(0)" ::: "memory");                                     \
    { /* V(k) transpose write into VC BEFORE the barrier (conflict-free swizzle) */      \
      int key2 = (t >> 3) * 2, c0 = (t & 7) * 8;                                         \
      _Pragma("unroll")                                                                  \
      for (int i = 0; i < 8; ++i) {                                                      \
        int dh = c0 + i;                                                                 \
        *(unsigned short*)(VC + dh * 128 +                                               \
            (key2 ^ ((dh & 7) << 4) ^ ((dh >> 4) << 5))) = VCC[i];                       \
      }                                                                                  \
    }                                                                                    \
    asm volatile("s_waitcnt lgkmcnt(0)" ::: "memory");                                   \
    __builtin_amdgcn_s_barrier();                                                        \
    __builtin_amdgcn_sched_barrier(0);                                                   \
    if ((KTV) + 1 < 16) { /* prefetch next tile (flies under compute) */                 \
      stageK(KN, (KTV) + 1);                                                             \
      const unsigned short* vsrc = Vg +                                                  \
          (size_t)(b * kS + ((KTV) + 1) * 64 + (t >> 3)) * ks_ + h * kDH + (t & 7) * 8;  \
      VNN = *reinterpret_cast<const ushort8*>(vsrc);                                     \
      MNXT = mtb[((KTV) + 1) * 512];                                                     \
    }                                                                                    \
    f32x4 sc[4];                                                                         \
    _Pragma("unroll")                                                                    \
    for (int ni = 0; ni < 4; ++ni) sc[ni] = f32x4{0.f, 0.f, 0.f, 0.f};                   \
    __builtin_amdgcn_s_setprio(1);                                                       \
    _Pragma("unroll")                                                                    \
    for (int ks = 0; ks < 2; ++ks) {                                                     \
      const int kb = ks * 64 + lg * 16;                                                  \
      ushort8 a = ks ? q1 : q0;                                                          \
      _Pragma("unroll")                                                                  \
      for (int ni = 0; ni < 4; ++ni) {                                                   \
        int kr = ni * 16 + l4;                                                           \
        ushort8 bb = *(const ushort8*)(KC + kr * 128 + (kb ^ ((kr & 7) << 4)));          \
        sc[ni] = mfma16(a, bb, sc[ni]);                                                  \
      }                                                                                  \
    }                                                                                    \
    __builtin_amdgcn_s_setprio(0);                                                       \
    const unsigned mbits_ = (unsigned)(MCUR);                                            \
    float tmax[4];                                                                       \
    _Pragma("unroll")                                                                    \
    for (int j = 0; j < 4; ++j) {                                                        \
      _Pragma("unroll")                                                                  \
      for (int ni = 0; ni < 4; ++ni)                                                     \
        if (!((mbits_ >> (ni * 4 + j)) & 1u)) sc[ni][j] = -1e9f;                         \
      tmax[j] = fmaxf(fmaxf(sc[0][j], sc[1][j]), fmaxf(sc[2][j], sc[3][j]));             \
    }                                                                                    \
    bool need = (tmax[0] > m_r[0] + 8.f) || (tmax[1] > m_r[1] + 8.f) ||                  \
                (tmax[2] > m_r[2] + 8.f) || (tmax[3] > m_r[3] + 8.f);                    \
    if (__any(need)) { /* rare after first tile: full reduce + rescale */                \
      _Pragma("unroll")                                                                  \
      for (int j = 0; j < 4; ++j) {                                                      \
        tmax[j] = fmaxf(tmax[j], __shfl_xor(tmax[j], 1, 64));                            \
        tmax[j] = fmaxf(tmax[j], __shfl_xor(tmax[j], 2, 64));                            \
        tmax[j] = fmaxf(tmax[j], __shfl_xor(tmax[j], 4, 64));                            \
        tmax[j] = fmaxf(tmax[j], __shfl_xor(tmax[j], 8, 64));                            \
        float mn = fmaxf(m_r[j], tmax[j]);                                               \
        float al = exp2f(m_r[j] - mn);                                                   \
        m_r[j] = mn;                                                                     \
        o[0][j] *= al; o[1][j] *= al; o[2][j] *= al; o[3][j] *= al;                      \
        l_acc[j] *= al;                                                                  \
      }                                                                                  \
    }                                                                                    \
    _Pragma("unroll")                                                                    \
    for (int ni = 0; ni < 4; ++ni)                                                       \
      _Pragma("unroll")                                                                  \
      for (int j = 0; j < 4; ++j)                                                        \
        sc[ni][j] = exp2f(sc[ni][j] - m_r[j]);                                           \
    { /* P -> per-wave LDS region, conflict-free swizzle */                              \
      char* Pw = Ps + w * 2048;                                                          \
      _Pragma("unroll")                                                                  \
      for (int ni = 0; ni < 4; ++ni)                                                     \
        _Pragma("unroll")                                                                \
        for (int j = 0; j < 4; ++j) {                                                    \
          int row = lg * 4 + j, col = ni * 16 + l4;                                      \
          *(unsigned short*)(Pw + row * 128 +                                            \
              ((col * 2) ^ ((row & 7) << 4) ^ ((row & 8) << 2))) =                       \
              __builtin_bit_cast(unsigned short, (__bf16)sc[ni][j]);                     \
        }                                                                                \
    }                                                                                    \
    asm volatile("s_waitcnt lgkmcnt(0)" ::: "memory");                                   \
    __builtin_amdgcn_sched_barrier(0);                                                   \
    __builtin_amdgcn_s_setprio(1);                                                       \
    { /* PV + l-accumulation via ones-MFMA */                                            \
      const char* Pw = Ps + w * 2048;                                                    \
      _Pragma("unroll")                                                                  \
      for (int ks = 0; ks < 2; ++ks) {                                                   \
        const int kb = ks * 64 + lg * 16;                                                \
        ushort8 pa = *(const ushort8*)(Pw + l4 * 128 +                                   \
            (kb ^ ((l4 & 7) << 4) ^ ((l4 & 8) << 2)));                                   \
        l_acc = mfma16(pa, onesv, l_acc);                                                \
        _Pragma("unroll")                                                                \
        for (int di = 0; di < 4; ++di) {                                                 \
          int vr2 = di * 16 + l4;                                                        \
          ushort8 vb = *(const ushort8*)(VC + vr2 * 128 +                                \
              (kb ^ ((vr2 & 7) << 4) ^ ((vr2 >> 4) << 5)));                              \
          o[di] = mfma16(pa, vb, o[di]);                                                 \
        }                                                                                \
      }                                                                                  \
    }                                                                                    \
    __builtin_amdgcn_s_setprio(0);                                                       \
  }

  for (int kt = 0; kt < 16; kt += 2) {
    ATTN_TILE(Ks0, VT0, Ks1, vA, vB, mA, mB, kt);
    ATTN_TILE(Ks1, VT1, Ks0, vB, vA, mB, mA, kt + 1);
  }
#undef ATTN_TILE

  // epilogue: l_acc[j] already holds the full row sum for q = lg*4+j
  float rinv[4];
#pragma unroll
  for (int j = 0; j < 4; ++j) rinv[j] = 1.0f / l_acc[j];
#pragma unroll
  for (int di = 0; di < 4; ++di) {
    int col = h * kDH + di * 16 + l4;
#pragma unroll
    for (int j = 0; j < 4; ++j) {
      int qrow = qt * 128 + w * 16 + lg * 4 + j;
      Og[(size_t)(b * kS + qrow) * kD + col] =
          __builtin_bit_cast(unsigned short, (__bf16)(o[di][j] * rinv[j]));
    }
  }
}

// ---------------------------------------------------------------------------
// out = LayerNorm(x + y0 + y1) * g + be (D=1024); all bf16 inputs; bf16 out
// and/or f32 out (either pointer may be null).
// ---------------------------------------------------------------------------
__global__ __launch_bounds__(256) void addln_kernel(
    const unsigned short* __restrict__ x, const unsigned short* __restrict__ y0,
    const unsigned short* __restrict__ y1,
    const float* __restrict__ g, const float* __restrict__ be,
    unsigned short* __restrict__ outb, float* __restrict__ outf)
{
  const int row = blockIdx.x, t = threadIdx.x;
  const size_t base = (size_t)row * 1024 + t * 4;
  ushort4v xv = *reinterpret_cast<const ushort4v*>(x + base);
  ushort4v yv0 = *reinterpret_cast<const ushort4v*>(y0 + base);
  ushort4v yv1 = *reinterpret_cast<const ushort4v*>(y1 + base);
  float v0 = bf2f(xv[0]) + bf2f(yv0[0]) + bf2f(yv1[0]);
  float v1 = bf2f(xv[1]) + bf2f(yv0[1]) + bf2f(yv1[1]);
  float v2 = bf2f(xv[2]) + bf2f(yv0[2]) + bf2f(yv1[2]);
  float v3 = bf2f(xv[3]) + bf2f(yv0[3]) + bf2f(yv1[3]);
  float s1 = v0 + v1 + v2 + v3;
  float s2 = v0 * v0 + v1 * v1 + v2 * v2 + v3 * v3;
#pragma unroll
  for (int off = 1; off < 64; off <<= 1) {
    s1 += __shfl_xor(s1, off, 64);
    s2 += __shfl_xor(s2, off, 64);
  }
  __shared__ float r1[4], r2[4];
  const int w = t >> 6, lane = t & 63;
  if (lane == 0) { r1[w] = s1; r2[w] = s2; }
  __syncthreads();
  s1 = r1[0] + r1[1] + r1[2] + r1[3];
  s2 = r2[0] + r2[1] + r2[2] + r2[3];
  const float mean = s1 * (1.0f / 1024.0f);
  const float var = s2 * (1.0f / 1024.0f) - mean * mean;
  const float rs = rsqrtf(var + 1e-5f);
  float4 gv = *reinterpret_cast<const float4*>(g + t * 4);
  float4 bv = *reinterpret_cast<const float4*>(be + t * 4);
  float4 ov;
  ov.x = (v0 - mean) * rs * gv.x + bv.x;
  ov.y = (v1 - mean) * rs * gv.y + bv.y;
  ov.z = (v2 - mean) * rs * gv.z + bv.z;
  ov.w = (v3 - mean) * rs * gv.w + bv.w;
  if (outb) {
    ushort4v bo;
    bo[0] = f2bf(ov.x); bo[1] = f2bf(ov.y); bo[2] = f2bf(ov.z); bo[3] = f2bf(ov.w);
    *reinterpret_cast<ushort4v*>(outb + base) = bo;
  }
  if (outf) *reinterpret_cast<float4*>(outf + base) = ov;
}

// ---------------------------------------------------------------------------
__global__ __launch_bounds__(256) void cvt2_bf16_kernel(
    const float* __restrict__ a, const float* __restrict__ b,
    unsigned short* __restrict__ da, unsigned short* __restrict__ db, int n8each)
{
  int i = blockIdx.x * 256 + threadIdx.x;
  const float* s = a; unsigned short* d = da;
  if (i >= n8each) { s = b; d = db; i -= n8each; }
  if (i >= n8each) return;
  float4 f0 = reinterpret_cast<const float4*>(s)[i * 2];
  float4 f1 = reinterpret_cast<const float4*>(s)[i * 2 + 1];
  ushort8 v;
  v[0] = f2bf(f0.x); v[1] = f2bf(f0.y); v[2] = f2bf(f0.z); v[3] = f2bf(f0.w);
  v[4] = f2bf(f1.x); v[5] = f2bf(f1.y); v[6] = f2bf(f1.z); v[7] = f2bf(f1.w);
  reinterpret_cast<ushort8*>(d)[i] = v;
}

// W[K][N] f32 -> Wt[n][k] bf16 (dst stride = K)
__global__ __launch_bounds__(256) void transpose_cvt_kernel(
    const float* __restrict__ src, unsigned short* __restrict__ dst, int K, int N)
{
  __shared__ float tile[32][33];
  const int bx = blockIdx.x, by = blockIdx.y;
  const int tx = threadIdx.x & 31, ty = threadIdx.x >> 5;
#pragma unroll
  for (int i = 0; i < 4; ++i)
    tile[ty + i * 8][tx] = src[(size_t)(by * 32 + ty + i * 8) * N + bx * 32 + tx];
  __syncthreads();
#pragma unroll
  for (int i = 0; i < 4; ++i)
    dst[(size_t)(bx * 32 + ty + i * 8) * K + by * 32 + tx] = f2bf(tile[tx][ty + i * 8]);
}

// batched 1024x1024 transposes with per-entry scale, grid (32,32,8)
struct TPtrs { const float* s[8]; unsigned short* d[8]; float scale[8]; };
__global__ __launch_bounds__(256) void tcvt_batch_kernel(TPtrs p)
{
  __shared__ float tile[32][33];
  const float* __restrict__ src = p.s[blockIdx.z];
  unsigned short* __restrict__ dst = p.d[blockIdx.z];
  const float sc = p.scale[blockIdx.z];
  const int bx = blockIdx.x, by = blockIdx.y;
  const int tx = threadIdx.x & 31, ty = threadIdx.x >> 5;
#pragma unroll
  for (int i = 0; i < 4; ++i)
    tile[ty + i * 8][tx] = src[(size_t)(by * 32 + ty + i * 8) * 1024 + bx * 32 + tx];
  __syncthreads();
#pragma unroll
  for (int i = 0; i < 4; ++i)
    dst[(size_t)(bx * 32 + ty + i * 8) * 1024 + by * 32 + tx] = f2bf(tile[tx][ty + i * 8] * sc);
}

__global__ void biasprep_kernel(const float* sq, const float* sk, const float* sv,
                                const float* cq, const float* ck, const float* cv,
                                float* bsa, float* bca, float s)
{
  int i = blockIdx.x * 256 + threadIdx.x;
  if (i < 1024)      { bsa[i] = sq[i] * s;        bca[i] = cq[i] * s; }
  else if (i < 2048) { bsa[i] = sk[i - 1024];     bca[i] = ck[i - 1024]; }
  else if (i < 3072) { bsa[i] = sv[i - 2048];     bca[i] = cv[i - 2048]; }
}

// mask int32 -> per-attn-thread 16-bit bitmask (512-thread blocks):
// mpack[((b*8+qt)*16+kt)*512 + t], bit (ni*4+j) = mask for
// q = qt*128 + ((t>>6)&7)*16 + ((t>>4)&3)*4 + j,  k = kt*64 + ni*16 + (t&15)
__global__ __launch_bounds__(256) void maskprep_kernel(
    const int* __restrict__ mask, unsigned short* __restrict__ mpack)
{
  int idx = blockIdx.x * 256 + threadIdx.x;   // 262144 slots
  int t = idx & 511;
  int kt = (idx >> 9) & 15;
  int qt = (idx >> 13) & 7;
  int b = idx >> 16;
  int qb = qt * 128 + ((t >> 6) & 7) * 16 + ((t >> 4) & 3) * 4;
  int kb = kt * 64 + (t & 15);
  unsigned m = 0;
#pragma unroll
  for (int ni = 0; ni < 4; ++ni)
#pragma unroll
    for (int j = 0; j < 4; ++j)
      if (mask[(size_t)(b * 1024 + qb + j) * 1024 + kb + ni * 16]) m |= 1u << (ni * 4 + j);
  mpack[idx] = (unsigned short)m;
}

// ---------------------------------------------------------------------------
extern "C" void kernel_launch(void* const* d_in, const int* in_sizes, int n_in,
                              void* d_out, int out_size, void* d_ws, size_t ws_size,
                              hipStream_t stream)
{
  const float* tgt  = (const float*)d_in[0];
  const float* memi = (const float*)d_in[1];
  const int*   mask = (const int*)d_in[2];
  const float* sa_wq = (const float*)d_in[3];  const float* sa_bq = (const float*)d_in[4];
  const float* sa_wk = (const float*)d_in[5];  const float* sa_bk = (const float*)d_in[6];
  const float* sa_wv = (const float*)d_in[7];  const float* sa_bv = (const float*)d_in[8];
  const float* sa_wo = (const float*)d_in[9];  const float* sa_bo = (const float*)d_in[10];
  const float* ca_wq = (const float*)d_in[11]; const float* ca_bq = (const float*)d_in[12];
  const float* ca_wk = (const float*)d_in[13]; const float* ca_bk = (const float*)d_in[14];
  const float* ca_wv = (const float*)d_in[15]; const float* ca_bv = (const float*)d_in[16];
  const float* ca_wo = (const float*)d_in[17]; const float* ca_bo = (const float*)d_in[18];
  const float* w1 = (const float*)d_in[19]; const float* b1 = (const float*)d_in[20];
  const float* w2 = (const float*)d_in[21]; const float* b2 = (const float*)d_in[22];
  const float* g1 = (const float*)d_in[23]; const float* be1 = (const float*)d_in[24];
  const float* g2 = (const float*)d_in[25]; const float* be2 = (const float*)d_in[26];
  const float* g3 = (const float*)d_in[27]; const float* be3 = (const float*)d_in[28];
  float* out = (float*)d_out;
  char* W = (char*)d_ws;
  const size_t MB = 1 << 20;
  typedef unsigned short us;
  const float QSCALE = 0.18033688011112042f;   // 0.125 * log2(e)

  // workspace layout (byte offsets; total ~106 MB).
  // NOTE: QKV spans 49-73MB, so T1b lives at 98MB (NOT inside 49-73).
  us* Wsaqkv = (us*)(W + 0);          // [3072][1024] bf16
  us* Wsao   = (us*)(W + 6 * MB);
  us* Wcaqkv = (us*)(W + 8 * MB);     // [3072][1024] = Wcaq | Wcakv contiguous
  us* Wcao   = (us*)(W + 14 * MB);
  us* W1t    = (us*)(W + 16 * MB);    // [4096][1024]
  us* W2t    = (us*)(W + 24 * MB);    // [1024][4096]
  float* b_saqkv = (float*)(W + 32 * MB);
  float* b_caqkv = (float*)(W + 32 * MB + 16384);
  us* tgt_bf = (us*)(W + 33 * MB);    // read by addln#1; then reused as T2b
  us* T2b    = tgt_bf;
  us* mem_bf = (us*)(W + 41 * MB);
  us* QKV    = (us*)(W + 49 * MB);    // [4096][3072] = 49-73MB (SA and CA reuse)
  us* AO     = (us*)(W + 73 * MB);    // [4096][1024] bf16, 73-81
  us* Hb     = (us*)(W + 49 * MB);    // FFN hidden [4096][4096] bf16 (49-81; QKV/AO dead)
  us* Opb    = (us*)(W + 81 * MB);    // TWO [4096][1024] bf16 partial slabs (81-97)
  us* mpack  = (us*)(W + 97 * MB);    // [4][8][16][512] ushort bitmasks, 512KB
  us* T1b    = (us*)(W + 98 * MB);    // [4096][1024] bf16, 98-106 (clear of QKV!)
  us* Opb1   = Opb + 4096 * 1024;

  const int M = 4096;
  dim3 blk(256);
  auto gemm = [&](const us* Aa, const us* Aa2, int nsplit, const us* Bta,
                  const float* bias, void* Cc, int Nn, int Kk, int flags, int zsplit) {
    gemm_bf16_kernel<<<dim3(Nn / 128, M / 128, zsplit), blk, 0, stream>>>(
        Aa, Aa2, nsplit, Bta, bias, Cc, M, Nn, Kk, flags);
  };

  // ---- prep ----
  TPtrs tp;
  tp.s[0] = sa_wq; tp.d[0] = Wsaqkv;               tp.scale[0] = QSCALE;
  tp.s[1] = sa_wk; tp.d[1] = Wsaqkv + 1024 * 1024; tp.scale[1] = 1.f;
  tp.s[2] = sa_wv; tp.d[2] = Wsaqkv + 2048 * 1024; tp.scale[2] = 1.f;
  tp.s[3] = sa_wo; tp.d[3] = Wsao;                 tp.scale[3] = 1.f;
  tp.s[4] = ca_wq; tp.d[4] = Wcaqkv;               tp.scale[4] = QSCALE;
  tp.s[5] = ca_wk; tp.d[5] = Wcaqkv + 1024 * 1024; tp.scale[5] = 1.f;
  tp.s[6] = ca_wv; tp.d[6] = Wcaqkv + 2048 * 1024; tp.scale[6] = 1.f;
  tp.s[7] = ca_wo; tp.d[7] = Wcao;                 tp.scale[7] = 1.f;
  tcvt_batch_kernel<<<dim3(32, 32, 8), blk, 0, stream>>>(tp);
  transpose_cvt_kernel<<<dim3(128, 32), blk, 0, stream>>>(w1, W1t, 1024, 4096);
  transpose_cvt_kernel<<<dim3(32, 128), blk, 0, stream>>>(w2, W2t, 4096, 1024);
  cvt2_bf16_kernel<<<dim3(4096), blk, 0, stream>>>(tgt, memi, tgt_bf, mem_bf, M * 1024 / 8);
  biasprep_kernel<<<dim3(12), blk, 0, stream>>>(sa_bq, sa_bk, sa_bv, ca_bq, ca_bk, ca_bv,
                                                b_saqkv, b_caqkv, QSCALE);
  maskprep_kernel<<<dim3(1024), blk, 0, stream>>>(mask, mpack);

  // ---- self-attention ----
  gemm(tgt_bf, tgt_bf, 1 << 30, Wsaqkv, b_saqkv, QKV, 3072, 1024, 2, 1);
  attn_kernel<<<dim3(8, 16, 4), dim3(512), 0, stream>>>(QKV, QKV + 1024, QKV + 2048, 3072, 3072, mpack, AO);
  gemm(AO, AO, 1 << 30, Wsao, sa_bo, Opb, 1024, 1024, 2, 2);   // split-K=2
  addln_kernel<<<dim3(M), blk, 0, stream>>>(tgt_bf, Opb, Opb1, g1, be1, T1b, nullptr);

  // ---- cross-attention (Q from T1b, K/V from mem_bf; one merged GEMM) ----
  gemm(T1b, mem_bf, 8, Wcaqkv, b_caqkv, QKV, 3072, 1024, 2, 1);
  attn_kernel<<<dim3(8, 16, 4), dim3(512), 0, stream>>>(QKV, QKV + 1024, QKV + 2048, 3072, 3072, mpack, AO);
  gemm(AO, AO, 1 << 30, Wcao, ca_bo, Opb, 1024, 1024, 2, 2);   // split-K=2
  addln_kernel<<<dim3(M), blk, 0, stream>>>(T1b, Opb, Opb1, g2, be2, T2b, nullptr);

  // ---- FFN ----
  gemm(T2b, T2b, 1 << 30, W1t, b1, Hb, 4096, 1024, 3, 1);
  gemm(Hb, Hb, 1 << 30, W2t, b2, Opb, 1024, 4096, 2, 2);       // split-K=2
  addln_kernel<<<dim3(M), blk, 0, stream>>>(T2b, Opb, Opb1, g3, be3, nullptr, out);

  (void)in_sizes; (void)n_in; (void)out_size; (void)ws_size;
}